// Round 6
// baseline (407.604 us; speedup 1.0000x reference)
//
#include <hip/hip_runtime.h>
#include <cstddef>

// ---- problem constants ----
constexpr int kN  = 16;
constexpr int kI  = 128;
constexpr int kHW = 24;
constexpr int kQ  = 576;    // 24*24
constexpr int kD  = 484;    // 22*22
constexpr int kDP = 512;    // padded d
constexpr int kPP = 676;    // 26*26 padded

// GEMM K-tiling (BK=64)
constexpr int kKT1 = 72;    // K1 = 4608 / 64
constexpr int kKT2 = 4;     // K2 = 256 / 64
constexpr int kKT3 = 4;     // K3 = 256 / 64

// ---- workspace layout ----
// half region (element offsets into _Float16*)
constexpr size_t H_XPAD   = 0;                          // [16][26][26][256] NHWC
constexpr size_t H_HPAD   = 2768896;                    // [16][26][26][256] NHWC
constexpr size_t H_APACK1 = 5537792;                    // 1792*4608 frag-tiled (256-row, BK64)
constexpr size_t H_APACK2 = 13795328;                   // 1024*256 frag-tiled
constexpr size_t H_APACK3 = 14057472;                   // 256*256 frag-tiled
constexpr size_t H_A16    = 14123008;                   // [16][576][256]
constexpr size_t H_H16    = 16482304;                   // [16][576][256]
constexpr size_t H_Q16C   = 18841600;                   // [16][256][576]  (c-major)
constexpr size_t H_KT16   = 21200896;                   // [128 head][512 d][32 c]
constexpr size_t H_VC16   = 23298048;                   // [128 head][32 c][512 d]
constexpr size_t HALF_ELEMS = 25395200;
constexpr size_t HALF_BYTES = HALF_ELEMS * 2;           // 50,790,400
// float region at d_ws + HALF_BYTES
constexpr size_t F_G = 0;                               // [16][1024][576]

constexpr size_t kXHGap = H_HPAD - H_XPAD;              // hpad - xpad element gap

using half8    = __attribute__((ext_vector_type(8))) _Float16;
using floatx16 = __attribute__((ext_vector_type(16))) float;

__device__ __forceinline__ float sigm(float x) { return 1.0f / (1.0f + __expf(-x)); }
__device__ __forceinline__ float tanh_f(float x) {
    float e = __expf(2.0f * fabsf(x));
    float r = 1.0f - 2.0f / (e + 1.0f);
    return copysignf(r, x);
}

// 16B-aligned vector load/store (emits b128 ops)
__device__ __forceinline__ half8 LD8(const _Float16* p) { return *(const half8*)p; }
__device__ __forceinline__ void ST8(_Float16* p, half8 v) { *(half8*)p = v; }

// ---------------- weight packing ----------------
// Apack layout (BK=64): [mt][kt][kk(4)][hl(2)][row(256)][j(8)] — exact A-fragment
// order, 256-row M-tiles.
// K-order for gemm1: k = src*2304 + tap*256 + ic
// Gate rows (m>=768) PERMUTED: dst row m' = 4*r + gate for the fused LSTM epilogue.
//
// R6 rewrite: COALESCED. Old version gathered with per-lane stride 9216B (lane
// walked m) -> ~64 cache lines per wave-load, ~2.4 GB of line traffic (~130 µs).
// Key fact: one contiguous 576-float span [mm*2304 + icb*576, +576) holds all
// 9 taps x 64 ics for one row -> serves NINE kt tiles from one coalesced read.
// Block = (mt, srcs, icb, rowgroup16): 36 coalesced wave-loads -> 36 KB LDS ->
// stride-9 LDS gather (2-way bank aliasing = free) -> half8 stores in fragment
// order. Each source float read exactly once: 66 MB read + 33 MB write.
__global__ __launch_bounds__(256)
void pack1_kernel(const float* __restrict__ wq_x, const float* __restrict__ wq_h,
                  const float* __restrict__ wk_x, const float* __restrict__ wk_h,
                  const float* __restrict__ wv_x, const float* __restrict__ wv_h,
                  const float* __restrict__ wg_x, const float* __restrict__ wg_h,
                  _Float16* __restrict__ dst) {
    __shared__ float ls[9216];                 // 16 rows x 576 floats
    const int bid = blockIdx.x;                // 7mt * 2srcs * 4icb * 16rg = 896
    const int rg   = bid & 15;
    const int icb  = (bid >> 4) & 3;
    const int srcs = (bid >> 6) & 1;
    const int mt   = bid >> 7;
    const int tid = threadIdx.x;

    const float *s1, *s2;
    if (mt == 0)      { s1 = wq_x; s2 = wq_h; }
    else if (mt == 1) { s1 = wk_x; s2 = wk_h; }
    else if (mt == 2) { s1 = wv_x; s2 = wv_h; }
    else              { s1 = wg_x; s2 = wg_h; }
    const float* sp = srcs ? s2 : s1;

    // cooperative coalesced load: 16 rows x 576 floats
    #pragma unroll
    for (int rep = 0; rep < 36; ++rep) {
        int f = rep * 256 + tid;
        int row = f / 576, off = f - row * 576;
        int mm;
        if (mt < 3) {
            mm = rg * 16 + row;
        } else {
            int mp = (mt - 3) * 256 + rg * 16 + row;     // m - 768
            mm = (mp & 3) * 256 + (mp >> 2);             // gate interleave
        }
        ls[f] = sp[(size_t)mm * 2304 + (size_t)icb * 576 + off];
    }
    __syncthreads();

    // write phase: 1152 chunks = 16 rows x 9 taps x 4 kk x 2 hl, half8 each
    const size_t mt_base = (size_t)mt * 72 * 16384;
    for (int c = tid; c < 1152; c += 256) {
        int row = c / 72, rem = c - row * 72;
        int tap = rem >> 3, khl = rem & 7;
        int kk = khl >> 1, hl = khl & 1;
        int kt = srcs * 36 + tap * 4 + icb;
        const float* lp = ls + row * 576 + (kk * 16 + hl * 8) * 9 + tap;
        half8 v;
        #pragma unroll
        for (int j = 0; j < 8; ++j) v[j] = (_Float16)lp[j * 9];
        ST8(dst + mt_base + (size_t)kt * 16384 + kk * 4096 + hl * 2048
                + (size_t)(rg * 16 + row) * 8, v);
    }
}

// PERM=1: dst row m <- src row (m&3)*256 + (m>>2)  (gate interleave for wg_a)
template<int PERM>
__global__ void pack_flat_kernel(const float* __restrict__ src, _Float16* __restrict__ dst,
                                 int Ktot, int Ktiles) {
    int p8 = blockIdx.x * 256 + threadIdx.x;           // one half8 per thread
    int row = p8 & 255, hl = (p8 >> 8) & 1, kk = (p8 >> 9) & 3;
    int tile = p8 >> 11;
    int mt = tile / Ktiles, kt = tile - mt * Ktiles;
    int m = mt * 256 + row;
    int k0 = kt * 64 + kk * 16 + hl * 8;
    int mm = PERM ? ((m & 3) * 256 + (m >> 2)) : m;
    const float* sp = src + (size_t)mm * Ktot + k0;
    half8 v;
    #pragma unroll
    for (int j = 0; j < 8; ++j) v[j] = (_Float16)sp[j];
    ST8(dst + (size_t)p8 * 8, v);
}

// ---------------- input staging ----------------
// h0 [n][256][576] fp32 -> NHWC fp16 padded [n][26][26][256] (borders pre-zeroed)
__global__ void pad_nhwc_kernel(const float* __restrict__ src, _Float16* __restrict__ dst) {
    __shared__ float tile[32][65];
    int pxt = blockIdx.x, ict = blockIdx.y, n = blockIdx.z;
    int tid = threadIdx.x;
    {
        int icl = tid >> 6, pxl = tid & 63;
        #pragma unroll
        for (int rep = 0; rep < 8; ++rep) {
            int ic = ict * 32 + rep * 4 + icl;
            tile[rep * 4 + icl][pxl] = src[((size_t)n * 256 + ic) * kQ + pxt * 64 + pxl];
        }
    }
    __syncthreads();
    {
        int icl = tid & 31, pxl0 = tid >> 5;
        #pragma unroll
        for (int rep = 0; rep < 8; ++rep) {
            int pxl = rep * 8 + pxl0;
            int px = pxt * 64 + pxl;
            int y = px / kHW, x = px - y * kHW;
            dst[((size_t)n * kPP + (size_t)(y + 1) * 26 + (x + 1)) * 256 + ict * 32 + icl] =
                (_Float16)tile[icl][pxl];
        }
    }
}

// xin = 1x1 conv(x, w_in)+b_in -> NHWC fp16 padded
__global__ void conv1x1_pad_kernel(const float* __restrict__ x, const float* __restrict__ w,
                                   const float* __restrict__ b, _Float16* __restrict__ out) {
    int px = blockIdx.x * 64 + threadIdx.x;
    int n = blockIdx.z;
    int oc0 = __builtin_amdgcn_readfirstlane(blockIdx.y * 16 + threadIdx.y * 4);
    const float* ip = x + (size_t)n * kI * kQ + px;
    float acc[4] = {0.f, 0.f, 0.f, 0.f};
    #pragma unroll 4
    for (int ic = 0; ic < kI; ++ic) {
        float xv = ip[(size_t)ic * kQ];
        #pragma unroll
        for (int j = 0; j < 4; ++j) acc[j] = fmaf(xv, w[(size_t)(oc0 + j) * kI + ic], acc[j]);
    }
    int y = px / kHW, xc = px - y * kHW;
    _Float16* op = out + ((size_t)n * kPP + (size_t)(y + 1) * 26 + (xc + 1)) * 256 + oc0;
    #pragma unroll
    for (int j = 0; j < 4; ++j) op[j] = (_Float16)(acc[j] + b[oc0 + j]);
}

// ---------------- fused MFMA GEMM (BK=64) ----------------
// (unchanged from R5 — frozen this round for clean attribution)
// BM=256, BN=64, BK=64; 256 threads = 4 waves; wave wv owns rows wv*64..+63.
// Raw s_barrier + manual lgkmcnt(0); counted vmcnt prefetches; setprio MFMA.
template<int BMODE, int EMODE>
__global__ __launch_bounds__(256, 3)
void gemm_kernel(const _Float16* __restrict__ Apack,
                 const _Float16* __restrict__ B1, const _Float16* __restrict__ B2,
                 _Float16* __restrict__ q16, _Float16* __restrict__ k16,
                 _Float16* __restrict__ v16, float* __restrict__ pf,
                 const float* __restrict__ bias, const float* __restrict__ c0p,
                 _Float16* __restrict__ h16o, int Ktiles, int Ktot) {
    __shared__ _Float16 Bs[2][4096];
    const int tid = threadIdx.x;
    const int wv = tid >> 6, lane = tid & 63, l31 = lane & 31, hl = lane >> 5;
    const int nt = blockIdx.x, n = blockIdx.y, mt = blockIdx.z;

    floatx16 acc00 = {}, acc01 = {}, acc10 = {}, acc11 = {};

    // A packed [mt][kt][kk4][hl2][row256][j8]; per-kt tile = 16384 elems
    const _Float16* abase = Apack + (size_t)mt * Ktiles * 16384;
    const int aoff = hl * 2048 + (wv * 64 + l31) * 8;      // + mi*256 + kk*4096

    // B staging: thread (px_l, bc) loads k-local [bc*16, +16) of row px_l
    const int px_l = tid >> 2, bc = tid & 3;
    const int px = nt * 64 + px_l;
    const int by = px / kHW, bx = px - by * kHW;

    // LDS swizzle: chunk ^= row&7 (8 chunks of 16B per 128B row)
    const int sw = px_l & 7;
    const int wofs0 = px_l * 64 + (((2 * bc) ^ sw) << 3);
    const int wofs1 = px_l * 64 + (((2 * bc + 1) ^ sw) << 3);
    const int rsw = l31 & 7;
    const int ro0 = l31 * 64 + (((0 + hl) ^ rsw) << 3);    // kkc0; +2048 for ci=1
    const int ro1 = l31 * 64 + (((2 + hl) ^ rsw) << 3);
    const int ro2 = l31 * 64 + (((4 + hl) ^ rsw) << 3);
    const int ro3 = l31 * 64 + (((6 + hl) ^ rsw) << 3);

    const _Float16* bsx;
    if (BMODE == 0) {
        bsx = B1 + ((size_t)n * kPP + (size_t)by * 26 + bx) * 256 + (size_t)bc * 16;
    } else {
        bsx = B1 + ((size_t)n * kQ + px) * Ktot + bc * 16;
    }

    auto loadB = [&](int kt, half8& lo, half8& hi) {
        if (BMODE == 0) {
            int srcs = (kt >= 36) ? 1 : 0;
            int ktl = kt - srcs * 36;
            int tap = ktl >> 2, icb = (ktl & 3) << 6;
            int ty = (tap * 11) >> 5;          // tap/3 for 0..9
            int tx = tap - ty * 3;
            const _Float16* p = bsx + (size_t)srcs * kXHGap
                              + ((size_t)(ty * 26 + tx)) * 256 + icb;
            lo = LD8(p); hi = LD8(p + 8);
        } else {
            const _Float16* p = bsx + kt * 64;
            lo = LD8(p); hi = LD8(p + 8);
        }
    };

    // prologue: B two tiles deep; A kkc01 of step 0
    half8 s0lo, s0hi, s1lo, s1hi;
    loadB(0, s0lo, s0hi);
    loadB(1, s1lo, s1hi);
    half8 eA = LD8(abase + aoff),        eB = LD8(abase + aoff + 256);
    half8 eC = LD8(abase + 4096 + aoff), eD = LD8(abase + 4096 + aoff + 256);
    half8 oA, oB, oC, oD;

    for (int kt = 0; kt < Ktiles; kt += 2) {
        const _Float16* ab = abase + (size_t)kt * 16384;
        // ---- even step: buffer 0 holds tile kt ----
        ST8(&Bs[0][wofs0], s0lo); ST8(&Bs[0][wofs1], s0hi);
        loadB(kt + 2, s0lo, s0hi);                          // 2-deep B prefetch
        asm volatile("s_waitcnt lgkmcnt(0)" ::: "memory");
        __builtin_amdgcn_s_barrier();                       // raw: no vmcnt drain
        {
            const _Float16* bb = Bs[0];
            half8 f0 = LD8(ab + 8192 + aoff),  f1 = LD8(ab + 8192 + aoff + 256);   // kkc2
            half8 f2 = LD8(ab + 12288 + aoff), f3 = LD8(ab + 12288 + aoff + 256);  // kkc3
            half8 b00 = LD8(bb + ro0), b01 = LD8(bb + ro0 + 2048);
            half8 b10 = LD8(bb + ro1), b11 = LD8(bb + ro1 + 2048);
            half8 b20 = LD8(bb + ro2), b21 = LD8(bb + ro2 + 2048);
            half8 b30 = LD8(bb + ro3), b31 = LD8(bb + ro3 + 2048);
            __builtin_amdgcn_s_setprio(1);
            acc00 = __builtin_amdgcn_mfma_f32_32x32x16_f16(eA, b00, acc00, 0, 0, 0);
            acc01 = __builtin_amdgcn_mfma_f32_32x32x16_f16(eA, b01, acc01, 0, 0, 0);
            acc10 = __builtin_amdgcn_mfma_f32_32x32x16_f16(eB, b00, acc10, 0, 0, 0);
            acc11 = __builtin_amdgcn_mfma_f32_32x32x16_f16(eB, b01, acc11, 0, 0, 0);
            acc00 = __builtin_amdgcn_mfma_f32_32x32x16_f16(eC, b10, acc00, 0, 0, 0);
            acc01 = __builtin_amdgcn_mfma_f32_32x32x16_f16(eC, b11, acc01, 0, 0, 0);
            acc10 = __builtin_amdgcn_mfma_f32_32x32x16_f16(eD, b10, acc10, 0, 0, 0);
            acc11 = __builtin_amdgcn_mfma_f32_32x32x16_f16(eD, b11, acc11, 0, 0, 0);
            __builtin_amdgcn_s_setprio(0);
            oA = LD8(ab + 16384 + aoff);        oB = LD8(ab + 16384 + aoff + 256); // next kkc01
            oC = LD8(ab + 16384 + 4096 + aoff); oD = LD8(ab + 16384 + 4096 + aoff + 256);
            __builtin_amdgcn_s_setprio(1);
            acc00 = __builtin_amdgcn_mfma_f32_32x32x16_f16(f0, b20, acc00, 0, 0, 0);
            acc01 = __builtin_amdgcn_mfma_f32_32x32x16_f16(f0, b21, acc01, 0, 0, 0);
            acc10 = __builtin_amdgcn_mfma_f32_32x32x16_f16(f1, b20, acc10, 0, 0, 0);
            acc11 = __builtin_amdgcn_mfma_f32_32x32x16_f16(f1, b21, acc11, 0, 0, 0);
            acc00 = __builtin_amdgcn_mfma_f32_32x32x16_f16(f2, b30, acc00, 0, 0, 0);
            acc01 = __builtin_amdgcn_mfma_f32_32x32x16_f16(f2, b31, acc01, 0, 0, 0);
            acc10 = __builtin_amdgcn_mfma_f32_32x32x16_f16(f3, b30, acc10, 0, 0, 0);
            acc11 = __builtin_amdgcn_mfma_f32_32x32x16_f16(f3, b31, acc11, 0, 0, 0);
            __builtin_amdgcn_s_setprio(0);
        }
        // ---- odd step: buffer 1 holds tile kt+1 ----
        const _Float16* ab2 = ab + 16384;
        ST8(&Bs[1][wofs0], s1lo); ST8(&Bs[1][wofs1], s1hi);
        loadB(kt + 3, s1lo, s1hi);
        asm volatile("s_waitcnt lgkmcnt(0)" ::: "memory");
        __builtin_amdgcn_s_barrier();
        {
            const _Float16* bb = Bs[1];
            half8 g0 = LD8(ab2 + 8192 + aoff),  g1 = LD8(ab2 + 8192 + aoff + 256);
            half8 g2 = LD8(ab2 + 12288 + aoff), g3 = LD8(ab2 + 12288 + aoff + 256);
            half8 b00 = LD8(bb + ro0), b01 = LD8(bb + ro0 + 2048);
            half8 b10 = LD8(bb + ro1), b11 = LD8(bb + ro1 + 2048);
            half8 b20 = LD8(bb + ro2), b21 = LD8(bb + ro2 + 2048);
            half8 b30 = LD8(bb + ro3), b31 = LD8(bb + ro3 + 2048);
            __builtin_amdgcn_s_setprio(1);
            acc00 = __builtin_amdgcn_mfma_f32_32x32x16_f16(oA, b00, acc00, 0, 0, 0);
            acc01 = __builtin_amdgcn_mfma_f32_32x32x16_f16(oA, b01, acc01, 0, 0, 0);
            acc10 = __builtin_amdgcn_mfma_f32_32x32x16_f16(oB, b00, acc10, 0, 0, 0);
            acc11 = __builtin_amdgcn_mfma_f32_32x32x16_f16(oB, b01, acc11, 0, 0, 0);
            acc00 = __builtin_amdgcn_mfma_f32_32x32x16_f16(oC, b10, acc00, 0, 0, 0);
            acc01 = __builtin_amdgcn_mfma_f32_32x32x16_f16(oC, b11, acc01, 0, 0, 0);
            acc10 = __builtin_amdgcn_mfma_f32_32x32x16_f16(oD, b10, acc10, 0, 0, 0);
            acc11 = __builtin_amdgcn_mfma_f32_32x32x16_f16(oD, b11, acc11, 0, 0, 0);
            __builtin_amdgcn_s_setprio(0);
            eA = LD8(ab2 + 16384 + aoff);        eB = LD8(ab2 + 16384 + aoff + 256);
            eC = LD8(ab2 + 16384 + 4096 + aoff); eD = LD8(ab2 + 16384 + 4096 + aoff + 256);
            __builtin_amdgcn_s_setprio(1);
            acc00 = __builtin_amdgcn_mfma_f32_32x32x16_f16(g0, b20, acc00, 0, 0, 0);
            acc01 = __builtin_amdgcn_mfma_f32_32x32x16_f16(g0, b21, acc01, 0, 0, 0);
            acc10 = __builtin_amdgcn_mfma_f32_32x32x16_f16(g1, b20, acc10, 0, 0, 0);
            acc11 = __builtin_amdgcn_mfma_f32_32x32x16_f16(g1, b21, acc11, 0, 0, 0);
            acc00 = __builtin_amdgcn_mfma_f32_32x32x16_f16(g2, b30, acc00, 0, 0, 0);
            acc01 = __builtin_amdgcn_mfma_f32_32x32x16_f16(g2, b31, acc01, 0, 0, 0);
            acc10 = __builtin_amdgcn_mfma_f32_32x32x16_f16(g3, b30, acc10, 0, 0, 0);
            acc11 = __builtin_amdgcn_mfma_f32_32x32x16_f16(g3, b31, acc11, 0, 0, 0);
            __builtin_amdgcn_s_setprio(0);
        }
    }

    // epilogue: C/D layout col=lane&31, row=(reg&3)+8*(reg>>2)+4*(lane>>5)
    if (EMODE == 3) {
        // fused gates+LSTM: reg q holds gate g=q&3 of channel rr (4 gates per reg-quad)
        const int rrb = mt * 64 + wv * 16;
        #pragma unroll
        for (int mi = 0; mi < 2; ++mi) {
            #pragma unroll
            for (int ci = 0; ci < 2; ++ci) {
                const floatx16& av = mi ? (ci ? acc11 : acc10) : (ci ? acc01 : acc00);
                const int pxe = nt * 64 + ci * 32 + l31;
                #pragma unroll
                for (int tq = 0; tq < 4; ++tq) {
                    int rr = rrb + mi * 8 + 2 * tq + hl;
                    size_t gb = ((size_t)n * 1024 + 4 * rr) * kQ + pxe;
                    float iv = av[4 * tq + 0] + pf[gb]          + bias[rr];
                    float fv = av[4 * tq + 1] + pf[gb + kQ]     + bias[256 + rr];
                    float gv = av[4 * tq + 2] + pf[gb + 2 * kQ] + bias[512 + rr];
                    float ov = av[4 * tq + 3] + pf[gb + 3 * kQ] + bias[768 + rr];
                    float cc = sigm(fv) * c0p[((size_t)n * 256 + rr) * kQ + pxe]
                             + sigm(iv) * tanh_f(gv);
                    float hh = sigm(ov) * tanh_f(cc);
                    h16o[((size_t)n * kQ + pxe) * 256 + rr] = (_Float16)hh;
                }
            }
        }
        return;
    }
    const int mb0 = mt * 256 + wv * 64;
    #pragma unroll
    for (int mi = 0; mi < 2; ++mi) {
        #pragma unroll
        for (int ci = 0; ci < 2; ++ci) {
            const floatx16& av = mi ? (ci ? acc11 : acc10) : (ci ? acc01 : acc00);
            const int pxe = nt * 64 + ci * 32 + l31;
            #pragma unroll
            for (int r = 0; r < 16; ++r) {
                int rowi = (r & 3) + 8 * (r >> 2) + 4 * hl;
                int m = mb0 + mi * 32 + rowi;
                float val = av[r];
                if (EMODE == 0) {
                    if (m < 256) {
                        q16[((size_t)n * 256 + m) * kQ + pxe] = (_Float16)val;
                    } else if (m < 768) {
                        int ch = m & 255;
                        int yy = pxe / kHW, xx = pxe - yy * kHW;
                        if (yy >= 1 && yy <= 22 && xx >= 1 && xx <= 22) {
                            int d = (yy - 1) * 22 + (xx - 1);
                            int head = n * 8 + (ch >> 5);
                            if (m < 512)
                                k16[((size_t)head * kDP + d) * 32 + (ch & 31)] = (_Float16)val;
                            else
                                v16[((size_t)head * 32 + (ch & 31)) * kDP + d] = (_Float16)(val + bias[ch]);
                        }
                    } else {
                        pf[((size_t)n * 1024 + (m - 768)) * kQ + pxe] = val;
                    }
                } else {
                    pf[((size_t)n * 256 + m) * kQ + pxe] = val + bias[m];
                }
            }
        }
    }
}

// ---------------- MFMA flash attention ----------------
__global__ __launch_bounds__(128)
void attn_kernel(const _Float16* __restrict__ q16c, const _Float16* __restrict__ kT16,
                 const _Float16* __restrict__ vC16, _Float16* __restrict__ a16) {
    const int lane = threadIdx.x & 63;
    const int wv   = threadIdx.x >> 6;
    const int l31 = lane & 31, hl = lane >> 5;
    // XCD-chunked swizzle (1152 blocks, 144/XCD): same-head blocks stay on one XCD
    const int lid = blockIdx.x + 9 * blockIdx.y;
    const int swz = (lid & 7) * 144 + (lid >> 3);
    const int bx = swz % 9, head = swz / 9;     // head = n*8 + hd
    const int n = head >> 3, hd = head & 7;
    const int qt = bx * 2 + wv;                 // 0..17
    const int q0 = qt * 32;

    half8 qf0, qf1;
    {
        const _Float16* qb = q16c + ((size_t)n * 256 + hd * 32 + hl * 8) * kQ + q0 + l31;
        #pragma unroll
        for (int j = 0; j < 8; ++j) {
            qf0[j] = qb[(size_t)j * kQ];
            qf1[j] = qb[(size_t)(16 + j) * kQ];
        }
    }

    const _Float16* kbase0 = kT16 + ((size_t)head * kDP + l31) * 32 + hl * 8;
    const _Float16* vbase0 = vC16 + ((size_t)head * 32 + l31) * kDP + hl * 8;

    floatx16 acc = {};
    float m_run = -1e30f, l_run = 0.f;

    half8 kf0 = LD8(kbase0);
    half8 kf1 = LD8(kbase0 + 16);

    for (int dt = 0; dt < 16; ++dt) {
        const int d0 = dt * 32;
        floatx16 S = {};
        S = __builtin_amdgcn_mfma_f32_32x32x16_f16(kf0, qf0, S, 0, 0, 0);
        S = __builtin_amdgcn_mfma_f32_32x32x16_f16(kf1, qf1, S, 0, 0, 0);

        half8 vf0 = LD8(vbase0 + d0);
        half8 vf1 = LD8(vbase0 + d0 + 16);
        if (dt < 15) {
            kf0 = LD8(kbase0 + (size_t)(d0 + 32) * 32);
            kf1 = LD8(kbase0 + (size_t)(d0 + 32) * 32 + 16);
        }

        if (dt == 15) {
            #pragma unroll
            for (int r = 0; r < 16; ++r)
                if (!(hl == 0 && r < 4)) S[r] = -1e30f;
        }

        float tmax = S[0];
        #pragma unroll
        for (int r = 1; r < 16; ++r) tmax = fmaxf(tmax, S[r]);
        tmax = fmaxf(tmax, __shfl_xor(tmax, 32));
        float mnew = fmaxf(m_run, tmax);
        float f = __expf(m_run - mnew);
        float p[16], psum = 0.f;
        #pragma unroll
        for (int r = 0; r < 16; ++r) { p[r] = __expf(S[r] - mnew); psum += p[r]; }
        psum += __shfl_xor(psum, 32);
        l_run = f * l_run + psum;
        #pragma unroll
        for (int r = 0; r < 16; ++r) acc[r] *= f;
        m_run = mnew;

        float other[16];
        #pragma unroll
        for (int r = 0; r < 16; ++r) other[r] = __shfl_xor(p[r], 32);
        half8 pf0, pf1;
        #pragma unroll
        for (int t = 0; t < 4; ++t) {
            pf0[t]     = (_Float16)(hl ? other[4 + t]  : p[t]);
            pf0[4 + t] = (_Float16)(hl ? p[4 + t]      : other[t]);
            pf1[t]     = (_Float16)(hl ? other[12 + t] : p[8 + t]);
            pf1[4 + t] = (_Float16)(hl ? p[12 + t]     : other[8 + t]);
        }

        acc = __builtin_amdgcn_mfma_f32_32x32x16_f16(vf0, pf0, acc, 0, 0, 0);
        acc = __builtin_amdgcn_mfma_f32_32x32x16_f16(vf1, pf1, acc, 0, 0, 0);
    }

    float inv = 1.f / l_run;
    _Float16* ap = a16 + ((size_t)n * kQ + q0 + l31) * 256 + hd * 32;
    #pragma unroll
    for (int r = 0; r < 16; ++r) {
        int c = (r & 3) + 8 * (r >> 2) + 4 * hl;
        ap[c] = (_Float16)(acc[r] * inv);
    }
}

extern "C" void kernel_launch(void* const* d_in, const int* in_sizes, int n_in,
                              void* d_out, int out_size, void* d_ws, size_t ws_size,
                              hipStream_t stream) {
    (void)in_sizes; (void)n_in; (void)out_size; (void)ws_size;
    const float* x     = (const float*)d_in[0];
    const float* h0    = (const float*)d_in[1];
    const float* c0    = (const float*)d_in[2];
    const float* w_in  = (const float*)d_in[3];
    const float* b_in  = (const float*)d_in[4];
    const float* wq_x  = (const float*)d_in[5];
    const float* wq_h  = (const float*)d_in[6];
    const float* wk_x  = (const float*)d_in[7];
    const float* wk_h  = (const float*)d_in[8];
    const float* wv_x  = (const float*)d_in[9];
    const float* wv_h  = (const float*)d_in[10];
    const float* bv    = (const float*)d_in[11];
    const float* wg_a  = (const float*)d_in[12];
    const float* bg    = (const float*)d_in[13];
    const float* wg_x  = (const float*)d_in[14];
    const float* wg_h  = (const float*)d_in[15];
    const float* w_out = (const float*)d_in[16];
    const float* b_out = (const float*)d_in[17];

    _Float16* wh = (_Float16*)d_ws;
    _Float16* xpad16  = wh + H_XPAD;
    _Float16* hpad16  = wh + H_HPAD;
    _Float16* apack1  = wh + H_APACK1;
    _Float16* apack2  = wh + H_APACK2;
    _Float16* apack3  = wh + H_APACK3;
    _Float16* a16     = wh + H_A16;
    _Float16* h16     = wh + H_H16;
    _Float16* q16c    = wh + H_Q16C;
    _Float16* kT16    = wh + H_KT16;
    _Float16* vC16    = wh + H_VC16;
    float* gbuf = (float*)((char*)d_ws + HALF_BYTES) + F_G;

    // zero NHWC image borders (ws re-poisoned each launch)
    hipMemsetAsync(wh, 0, 11075584, stream);

    // weight packing (fragment-order BK=64 tiles; gate rows interleaved)
    // pack1: coalesced LDS-transpose, 896 blocks (7mt x 2srcs x 4icb x 16rg)
    pack1_kernel<<<896, 256, 0, stream>>>(wq_x, wq_h, wk_x, wk_h, wv_x, wv_h, wg_x, wg_h, apack1);
    pack_flat_kernel<1><<<128, 256, 0, stream>>>(wg_a, apack2, 256, kKT2);
    pack_flat_kernel<0><<<32, 256, 0, stream>>>(w_out, apack3, 256, kKT3);

    // input staging (NHWC fp16)
    pad_nhwc_kernel<<<dim3(9, 8, kN), 256, 0, stream>>>(h0, hpad16);
    conv1x1_pad_kernel<<<dim3(9, 16, kN), dim3(64, 4), 0, stream>>>(x, w_in, b_in, xpad16);

    // fused q/k/v/gates3x3 GEMM: M=1792, K=4608, N=576 x 16 batches
    gemm_kernel<0, 0><<<dim3(9, kN, 7), 256, 0, stream>>>(
        apack1, xpad16, hpad16, q16c, kT16, vC16, gbuf, bv, nullptr, nullptr, kKT1, 0);

    // MFMA flash attention -> a16 [n][px][256]
    attn_kernel<<<dim3(9, 128), 128, 0, stream>>>(q16c, kT16, vC16, a16);

    // gates = wg_a . a + bg + gbuf, fused LSTM -> h16 [n][px][256]
    gemm_kernel<1, 3><<<dim3(9, kN, 4), 256, 0, stream>>>(
        apack2, a16, nullptr, nullptr, nullptr, nullptr, gbuf, bg, c0, h16, kKT2, 256);

    // out = w_out . h + b_out : M=256 -> 1 m-tile
    gemm_kernel<1, 2><<<dim3(9, kN, 1), 256, 0, stream>>>(
        apack3, h16, nullptr, nullptr, nullptr, nullptr, (float*)d_out, b_out, nullptr, nullptr, kKT3, 256);
}

// Round 7
// 400.247 us; speedup vs baseline: 1.0184x; 1.0184x over previous
//
#include <hip/hip_runtime.h>
#include <cstddef>

// ---- problem constants ----
constexpr int kN  = 16;
constexpr int kI  = 128;
constexpr int kHW = 24;
constexpr int kQ  = 576;    // 24*24
constexpr int kD  = 484;    // 22*22
constexpr int kDP = 512;    // padded d
constexpr int kPP = 676;    // 26*26 padded

// GEMM K-tiling (BK=64)
constexpr int kKT1 = 72;    // K1 = 4608 / 64
constexpr int kKT2 = 4;     // K2 = 256 / 64
constexpr int kKT3 = 4;     // K3 = 256 / 64

// ---- workspace layout ----
// half region (element offsets into _Float16*)
constexpr size_t H_XPAD   = 0;                          // [16][26][26][256] NHWC
constexpr size_t H_HPAD   = 2768896;                    // [16][26][26][256] NHWC
constexpr size_t H_APACK1 = 5537792;                    // 1792*4608 frag-tiled (256-row, BK64)
constexpr size_t H_APACK2 = 13795328;                   // 1024*256 frag-tiled
constexpr size_t H_APACK3 = 14057472;                   // 256*256 frag-tiled
constexpr size_t H_A16    = 14123008;                   // [16][576][256]
constexpr size_t H_H16    = 16482304;                   // [16][576][256]
constexpr size_t H_Q16C   = 18841600;                   // [16][256][576]  (c-major)
constexpr size_t H_KT16   = 21200896;                   // [128 head][512 d][32 c]
constexpr size_t H_VC16   = 23298048;                   // [128 head][32 c][512 d]
constexpr size_t HALF_ELEMS = 25395200;
constexpr size_t HALF_BYTES = HALF_ELEMS * 2;           // 50,790,400
// float region at d_ws + HALF_BYTES
constexpr size_t F_G = 0;                               // [16][1024][576]

constexpr size_t kXHGap = H_HPAD - H_XPAD;              // hpad - xpad element gap

using half8    = __attribute__((ext_vector_type(8))) _Float16;
using floatx16 = __attribute__((ext_vector_type(16))) float;

__device__ __forceinline__ float sigm(float x) { return 1.0f / (1.0f + __expf(-x)); }
__device__ __forceinline__ float tanh_f(float x) {
    float e = __expf(2.0f * fabsf(x));
    float r = 1.0f - 2.0f / (e + 1.0f);
    return copysignf(r, x);
}

// 16B-aligned vector load/store (emits b128 ops)
__device__ __forceinline__ half8 LD8(const _Float16* p) { return *(const half8*)p; }
__device__ __forceinline__ void ST8(_Float16* p, half8 v) { *(half8*)p = v; }

// ---------------- weight packing ----------------
// Apack layout (BK=64): [mt][kt][kk(4)][hl(2)][row(256)][j(8)] — exact A-fragment
// order, 256-row M-tiles. Coalesced LDS-transpose (R6).
// K-order for gemm1: k = src*2304 + tap*256 + ic
// Gate rows (m>=768) PERMUTED: dst row m' = 4*r + gate for the fused LSTM epilogue.
__global__ __launch_bounds__(256)
void pack1_kernel(const float* __restrict__ wq_x, const float* __restrict__ wq_h,
                  const float* __restrict__ wk_x, const float* __restrict__ wk_h,
                  const float* __restrict__ wv_x, const float* __restrict__ wv_h,
                  const float* __restrict__ wg_x, const float* __restrict__ wg_h,
                  _Float16* __restrict__ dst) {
    __shared__ float ls[9216];                 // 16 rows x 576 floats
    const int bid = blockIdx.x;                // 7mt * 2srcs * 4icb * 16rg = 896
    const int rg   = bid & 15;
    const int icb  = (bid >> 4) & 3;
    const int srcs = (bid >> 6) & 1;
    const int mt   = bid >> 7;
    const int tid = threadIdx.x;

    const float *s1, *s2;
    if (mt == 0)      { s1 = wq_x; s2 = wq_h; }
    else if (mt == 1) { s1 = wk_x; s2 = wk_h; }
    else if (mt == 2) { s1 = wv_x; s2 = wv_h; }
    else              { s1 = wg_x; s2 = wg_h; }
    const float* sp = srcs ? s2 : s1;

    // cooperative coalesced load: 16 rows x 576 floats
    #pragma unroll
    for (int rep = 0; rep < 36; ++rep) {
        int f = rep * 256 + tid;
        int row = f / 576, off = f - row * 576;
        int mm;
        if (mt < 3) {
            mm = rg * 16 + row;
        } else {
            int mp = (mt - 3) * 256 + rg * 16 + row;     // m - 768
            mm = (mp & 3) * 256 + (mp >> 2);             // gate interleave
        }
        ls[f] = sp[(size_t)mm * 2304 + (size_t)icb * 576 + off];
    }
    __syncthreads();

    // write phase: 1152 chunks = 16 rows x 9 taps x 4 kk x 2 hl, half8 each
    const size_t mt_base = (size_t)mt * 72 * 16384;
    for (int c = tid; c < 1152; c += 256) {
        int row = c / 72, rem = c - row * 72;
        int tap = rem >> 3, khl = rem & 7;
        int kk = khl >> 1, hl = khl & 1;
        int kt = srcs * 36 + tap * 4 + icb;
        const float* lp = ls + row * 576 + (kk * 16 + hl * 8) * 9 + tap;
        half8 v;
        #pragma unroll
        for (int j = 0; j < 8; ++j) v[j] = (_Float16)lp[j * 9];
        ST8(dst + mt_base + (size_t)kt * 16384 + kk * 4096 + hl * 2048
                + (size_t)(rg * 16 + row) * 8, v);
    }
}

// PERM=1: dst row m <- src row (m&3)*256 + (m>>2)  (gate interleave for wg_a)
template<int PERM>
__global__ void pack_flat_kernel(const float* __restrict__ src, _Float16* __restrict__ dst,
                                 int Ktot, int Ktiles) {
    int p8 = blockIdx.x * 256 + threadIdx.x;           // one half8 per thread
    int row = p8 & 255, hl = (p8 >> 8) & 1, kk = (p8 >> 9) & 3;
    int tile = p8 >> 11;
    int mt = tile / Ktiles, kt = tile - mt * Ktiles;
    int m = mt * 256 + row;
    int k0 = kt * 64 + kk * 16 + hl * 8;
    int mm = PERM ? ((m & 3) * 256 + (m >> 2)) : m;
    const float* sp = src + (size_t)mm * Ktot + k0;
    half8 v;
    #pragma unroll
    for (int j = 0; j < 8; ++j) v[j] = (_Float16)sp[j];
    ST8(dst + (size_t)p8 * 8, v);
}

// ---------------- input staging ----------------
// h0 [n][256][576] fp32 -> NHWC fp16 padded [n][26][26][256] (borders pre-zeroed)
__global__ void pad_nhwc_kernel(const float* __restrict__ src, _Float16* __restrict__ dst) {
    __shared__ float tile[32][65];
    int pxt = blockIdx.x, ict = blockIdx.y, n = blockIdx.z;
    int tid = threadIdx.x;
    {
        int icl = tid >> 6, pxl = tid & 63;
        #pragma unroll
        for (int rep = 0; rep < 8; ++rep) {
            int ic = ict * 32 + rep * 4 + icl;
            tile[rep * 4 + icl][pxl] = src[((size_t)n * 256 + ic) * kQ + pxt * 64 + pxl];
        }
    }
    __syncthreads();
    {
        int icl = tid & 31, pxl0 = tid >> 5;
        #pragma unroll
        for (int rep = 0; rep < 8; ++rep) {
            int pxl = rep * 8 + pxl0;
            int px = pxt * 64 + pxl;
            int y = px / kHW, x = px - y * kHW;
            dst[((size_t)n * kPP + (size_t)(y + 1) * 26 + (x + 1)) * 256 + ict * 32 + icl] =
                (_Float16)tile[icl][pxl];
        }
    }
}

// xin = 1x1 conv(x, w_in)+b_in -> NHWC fp16 padded
__global__ void conv1x1_pad_kernel(const float* __restrict__ x, const float* __restrict__ w,
                                   const float* __restrict__ b, _Float16* __restrict__ out) {
    int px = blockIdx.x * 64 + threadIdx.x;
    int n = blockIdx.z;
    int oc0 = __builtin_amdgcn_readfirstlane(blockIdx.y * 16 + threadIdx.y * 4);
    const float* ip = x + (size_t)n * kI * kQ + px;
    float acc[4] = {0.f, 0.f, 0.f, 0.f};
    #pragma unroll 4
    for (int ic = 0; ic < kI; ++ic) {
        float xv = ip[(size_t)ic * kQ];
        #pragma unroll
        for (int j = 0; j < 4; ++j) acc[j] = fmaf(xv, w[(size_t)(oc0 + j) * kI + ic], acc[j]);
    }
    int y = px / kHW, xc = px - y * kHW;
    _Float16* op = out + ((size_t)n * kPP + (size_t)(y + 1) * 26 + (xc + 1)) * 256 + oc0;
    #pragma unroll
    for (int j = 0; j < 4; ++j) op[j] = (_Float16)(acc[j] + b[oc0 + j]);
}

// ---------------- fused MFMA GEMM (BK=64, batch-pair) ----------------
// R7: each block computes TWO n-batches with ONE A read. gemm1 was VMEM-return
// bound (~3 GB L2->CU at ~66 B/cyc/CU >= the 56 B/cyc ceiling): A re-read 144x.
// Pairing n halves A traffic (2.38->1.19 GB) and doubles MFMA per A-byte.
// Grid 504 blocks @ 2 blocks/CU (reg-bound) = single round, no tail.
// BM=256, BN=64x2n, BK=64; 4 waves; wave owns 64 rows; 8 accs (2n x 2mi x 2ci).
// A loads issued BEFORE the barrier, AFTER the B stage-stores but BEFORE the
// B stage-prefetch loads, so the MFMA's vmcnt wait covers A but leaves the
// 2-deep B prefetch in flight (vmcnt retires in issue order).
// Raw s_barrier + lgkmcnt(0) only (counted vmcnt kept — R4).
template<int BMODE, int EMODE>
__global__ __launch_bounds__(256, 2)
void gemm_kernel(const _Float16* __restrict__ Apack,
                 const _Float16* __restrict__ B1, const _Float16* __restrict__ B2,
                 _Float16* __restrict__ q16, _Float16* __restrict__ k16,
                 _Float16* __restrict__ v16, float* __restrict__ pf,
                 const float* __restrict__ bias, const float* __restrict__ c0p,
                 _Float16* __restrict__ h16o, int Ktiles, int Ktot) {
    __shared__ _Float16 Bs[2][2][4096];        // [dbuf][nidx][64px*64k]
    const int tid = threadIdx.x;
    const int wv = tid >> 6, lane = tid & 63, l31 = lane & 31, hl = lane >> 5;
    const int nt = blockIdx.x, np = blockIdx.y, mt = blockIdx.z;
    const int n0 = np * 2;

    floatx16 c0_00 = {}, c0_01 = {}, c0_10 = {}, c0_11 = {};   // n0: mi,ci
    floatx16 c1_00 = {}, c1_01 = {}, c1_10 = {}, c1_11 = {};   // n1

    // A packed [mt][kt][kk4][hl2][row256][j8]; per-kt tile = 16384 elems
    const _Float16* abase = Apack + (size_t)mt * Ktiles * 16384;
    const int aoff = hl * 2048 + (wv * 64 + l31) * 8;

    // B staging: thread (px_l, bc) loads k-local [bc*16,+16) of row px_l, per n
    const int px_l = tid >> 2, bc = tid & 3;
    const int px = nt * 64 + px_l;
    const int by = px / kHW, bx = px - by * kHW;

    // LDS swizzle: chunk ^= row&7 (8 chunks of 16B per 128B row)
    const int sw = px_l & 7;
    const int wofs0 = px_l * 64 + (((2 * bc) ^ sw) << 3);
    const int wofs1 = px_l * 64 + (((2 * bc + 1) ^ sw) << 3);
    const int rsw = l31 & 7;
    const int ro0 = l31 * 64 + (((0 + hl) ^ rsw) << 3);    // kkc0; +2048 for ci=1
    const int ro1 = l31 * 64 + (((2 + hl) ^ rsw) << 3);
    const int ro2 = l31 * 64 + (((4 + hl) ^ rsw) << 3);
    const int ro3 = l31 * 64 + (((6 + hl) ^ rsw) << 3);

    const _Float16 *bsx0, *bsx1;
    if (BMODE == 0) {
        bsx0 = B1 + ((size_t)n0 * kPP + (size_t)by * 26 + bx) * 256 + (size_t)bc * 16;
        bsx1 = bsx0 + (size_t)kPP * 256;
    } else {
        bsx0 = B1 + ((size_t)n0 * kQ + px) * Ktot + bc * 16;
        bsx1 = bsx0 + (size_t)kQ * Ktot;
    }

    auto loadB = [&](const _Float16* base, int kt, half8& lo, half8& hi) {
        if (BMODE == 0) {
            int srcs = (kt >= 36) ? 1 : 0;
            int ktl = kt - srcs * 36;
            int tap = ktl >> 2, icb = (ktl & 3) << 6;
            int ty = (tap * 11) >> 5;          // tap/3 for 0..9
            int tx = tap - ty * 3;
            const _Float16* p = base + (size_t)srcs * kXHGap
                              + ((size_t)(ty * 26 + tx)) * 256 + icb;
            lo = LD8(p); hi = LD8(p + 8);
        } else {
            const _Float16* p = base + kt * 64;
            lo = LD8(p); hi = LD8(p + 8);
        }
    };

    // prologue: B two tiles deep for both n
    half8 e0l, e0h, e1l, e1h, o0l, o0h, o1l, o1h;
    loadB(bsx0, 0, e0l, e0h); loadB(bsx1, 0, e1l, e1h);
    loadB(bsx0, 1, o0l, o0h); loadB(bsx1, 1, o1l, o1h);

    for (int kt = 0; kt < Ktiles; kt += 2) {
        const _Float16* ab = abase + (size_t)kt * 16384;
        // ================= even step: buffer 0 = tile kt =================
        ST8(&Bs[0][0][wofs0], e0l); ST8(&Bs[0][0][wofs1], e0h);
        ST8(&Bs[0][1][wofs0], e1l); ST8(&Bs[0][1][wofs1], e1h);
        half8 aA = LD8(ab + aoff),          aB = LD8(ab + aoff + 256);          // kkc0
        half8 aC = LD8(ab + 4096 + aoff),   aD = LD8(ab + 4096 + aoff + 256);   // kkc1
        half8 f0 = LD8(ab + 8192 + aoff),   f1 = LD8(ab + 8192 + aoff + 256);   // kkc2
        half8 f2 = LD8(ab + 12288 + aoff),  f3 = LD8(ab + 12288 + aoff + 256);  // kkc3
        loadB(bsx0, kt + 2, e0l, e0h); loadB(bsx1, kt + 2, e1l, e1h);           // 2-deep B
        asm volatile("s_waitcnt lgkmcnt(0)" ::: "memory");
        __builtin_amdgcn_s_barrier();
        {
            const _Float16* bb0 = Bs[0][0];
            const _Float16* bb1 = Bs[0][1];
            half8 b00 = LD8(bb0 + ro0), b01 = LD8(bb0 + ro0 + 2048);
            half8 b10 = LD8(bb0 + ro1), b11 = LD8(bb0 + ro1 + 2048);
            __builtin_amdgcn_s_setprio(1);
            c0_00 = __builtin_amdgcn_mfma_f32_32x32x16_f16(aA, b00, c0_00, 0, 0, 0);
            c0_01 = __builtin_amdgcn_mfma_f32_32x32x16_f16(aA, b01, c0_01, 0, 0, 0);
            c0_10 = __builtin_amdgcn_mfma_f32_32x32x16_f16(aB, b00, c0_10, 0, 0, 0);
            c0_11 = __builtin_amdgcn_mfma_f32_32x32x16_f16(aB, b01, c0_11, 0, 0, 0);
            c0_00 = __builtin_amdgcn_mfma_f32_32x32x16_f16(aC, b10, c0_00, 0, 0, 0);
            c0_01 = __builtin_amdgcn_mfma_f32_32x32x16_f16(aC, b11, c0_01, 0, 0, 0);
            c0_10 = __builtin_amdgcn_mfma_f32_32x32x16_f16(aD, b10, c0_10, 0, 0, 0);
            c0_11 = __builtin_amdgcn_mfma_f32_32x32x16_f16(aD, b11, c0_11, 0, 0, 0);
            __builtin_amdgcn_s_setprio(0);
            b00 = LD8(bb0 + ro2); b01 = LD8(bb0 + ro2 + 2048);
            b10 = LD8(bb0 + ro3); b11 = LD8(bb0 + ro3 + 2048);
            __builtin_amdgcn_s_setprio(1);
            c0_00 = __builtin_amdgcn_mfma_f32_32x32x16_f16(f0, b00, c0_00, 0, 0, 0);
            c0_01 = __builtin_amdgcn_mfma_f32_32x32x16_f16(f0, b01, c0_01, 0, 0, 0);
            c0_10 = __builtin_amdgcn_mfma_f32_32x32x16_f16(f1, b00, c0_10, 0, 0, 0);
            c0_11 = __builtin_amdgcn_mfma_f32_32x32x16_f16(f1, b01, c0_11, 0, 0, 0);
            c0_00 = __builtin_amdgcn_mfma_f32_32x32x16_f16(f2, b10, c0_00, 0, 0, 0);
            c0_01 = __builtin_amdgcn_mfma_f32_32x32x16_f16(f2, b11, c0_01, 0, 0, 0);
            c0_10 = __builtin_amdgcn_mfma_f32_32x32x16_f16(f3, b10, c0_10, 0, 0, 0);
            c0_11 = __builtin_amdgcn_mfma_f32_32x32x16_f16(f3, b11, c0_11, 0, 0, 0);
            __builtin_amdgcn_s_setprio(0);
            b00 = LD8(bb1 + ro0); b01 = LD8(bb1 + ro0 + 2048);
            b10 = LD8(bb1 + ro1); b11 = LD8(bb1 + ro1 + 2048);
            __builtin_amdgcn_s_setprio(1);
            c1_00 = __builtin_amdgcn_mfma_f32_32x32x16_f16(aA, b00, c1_00, 0, 0, 0);
            c1_01 = __builtin_amdgcn_mfma_f32_32x32x16_f16(aA, b01, c1_01, 0, 0, 0);
            c1_10 = __builtin_amdgcn_mfma_f32_32x32x16_f16(aB, b00, c1_10, 0, 0, 0);
            c1_11 = __builtin_amdgcn_mfma_f32_32x32x16_f16(aB, b01, c1_11, 0, 0, 0);
            c1_00 = __builtin_amdgcn_mfma_f32_32x32x16_f16(aC, b10, c1_00, 0, 0, 0);
            c1_01 = __builtin_amdgcn_mfma_f32_32x32x16_f16(aC, b11, c1_01, 0, 0, 0);
            c1_10 = __builtin_amdgcn_mfma_f32_32x32x16_f16(aD, b10, c1_10, 0, 0, 0);
            c1_11 = __builtin_amdgcn_mfma_f32_32x32x16_f16(aD, b11, c1_11, 0, 0, 0);
            __builtin_amdgcn_s_setprio(0);
            b00 = LD8(bb1 + ro2); b01 = LD8(bb1 + ro2 + 2048);
            b10 = LD8(bb1 + ro3); b11 = LD8(bb1 + ro3 + 2048);
            __builtin_amdgcn_s_setprio(1);
            c1_00 = __builtin_amdgcn_mfma_f32_32x32x16_f16(f0, b00, c1_00, 0, 0, 0);
            c1_01 = __builtin_amdgcn_mfma_f32_32x32x16_f16(f0, b01, c1_01, 0, 0, 0);
            c1_10 = __builtin_amdgcn_mfma_f32_32x32x16_f16(f1, b00, c1_10, 0, 0, 0);
            c1_11 = __builtin_amdgcn_mfma_f32_32x32x16_f16(f1, b01, c1_11, 0, 0, 0);
            c1_00 = __builtin_amdgcn_mfma_f32_32x32x16_f16(f2, b10, c1_00, 0, 0, 0);
            c1_01 = __builtin_amdgcn_mfma_f32_32x32x16_f16(f2, b11, c1_01, 0, 0, 0);
            c1_10 = __builtin_amdgcn_mfma_f32_32x32x16_f16(f3, b10, c1_10, 0, 0, 0);
            c1_11 = __builtin_amdgcn_mfma_f32_32x32x16_f16(f3, b11, c1_11, 0, 0, 0);
            __builtin_amdgcn_s_setprio(0);
        }
        // ================= odd step: buffer 1 = tile kt+1 =================
        const _Float16* ab2 = ab + 16384;
        ST8(&Bs[1][0][wofs0], o0l); ST8(&Bs[1][0][wofs1], o0h);
        ST8(&Bs[1][1][wofs0], o1l); ST8(&Bs[1][1][wofs1], o1h);
        half8 gA = LD8(ab2 + aoff),          gB = LD8(ab2 + aoff + 256);
        half8 gC = LD8(ab2 + 4096 + aoff),   gD = LD8(ab2 + 4096 + aoff + 256);
        half8 g0 = LD8(ab2 + 8192 + aoff),   g1 = LD8(ab2 + 8192 + aoff + 256);
        half8 g2 = LD8(ab2 + 12288 + aoff),  g3 = LD8(ab2 + 12288 + aoff + 256);
        loadB(bsx0, kt + 3, o0l, o0h); loadB(bsx1, kt + 3, o1l, o1h);
        asm volatile("s_waitcnt lgkmcnt(0)" ::: "memory");
        __builtin_amdgcn_s_barrier();
        {
            const _Float16* bb0 = Bs[1][0];
            const _Float16* bb1 = Bs[1][1];
            half8 b00 = LD8(bb0 + ro0), b01 = LD8(bb0 + ro0 + 2048);
            half8 b10 = LD8(bb0 + ro1), b11 = LD8(bb0 + ro1 + 2048);
            __builtin_amdgcn_s_setprio(1);
            c0_00 = __builtin_amdgcn_mfma_f32_32x32x16_f16(gA, b00, c0_00, 0, 0, 0);
            c0_01 = __builtin_amdgcn_mfma_f32_32x32x16_f16(gA, b01, c0_01, 0, 0, 0);
            c0_10 = __builtin_amdgcn_mfma_f32_32x32x16_f16(gB, b00, c0_10, 0, 0, 0);
            c0_11 = __builtin_amdgcn_mfma_f32_32x32x16_f16(gB, b01, c0_11, 0, 0, 0);
            c0_00 = __builtin_amdgcn_mfma_f32_32x32x16_f16(gC, b10, c0_00, 0, 0, 0);
            c0_01 = __builtin_amdgcn_mfma_f32_32x32x16_f16(gC, b11, c0_01, 0, 0, 0);
            c0_10 = __builtin_amdgcn_mfma_f32_32x32x16_f16(gD, b10, c0_10, 0, 0, 0);
            c0_11 = __builtin_amdgcn_mfma_f32_32x32x16_f16(gD, b11, c0_11, 0, 0, 0);
            __builtin_amdgcn_s_setprio(0);
            b00 = LD8(bb0 + ro2); b01 = LD8(bb0 + ro2 + 2048);
            b10 = LD8(bb0 + ro3); b11 = LD8(bb0 + ro3 + 2048);
            __builtin_amdgcn_s_setprio(1);
            c0_00 = __builtin_amdgcn_mfma_f32_32x32x16_f16(g0, b00, c0_00, 0, 0, 0);
            c0_01 = __builtin_amdgcn_mfma_f32_32x32x16_f16(g0, b01, c0_01, 0, 0, 0);
            c0_10 = __builtin_amdgcn_mfma_f32_32x32x16_f16(g1, b00, c0_10, 0, 0, 0);
            c0_11 = __builtin_amdgcn_mfma_f32_32x32x16_f16(g1, b01, c0_11, 0, 0, 0);
            c0_00 = __builtin_amdgcn_mfma_f32_32x32x16_f16(g2, b10, c0_00, 0, 0, 0);
            c0_01 = __builtin_amdgcn_mfma_f32_32x32x16_f16(g2, b11, c0_01, 0, 0, 0);
            c0_10 = __builtin_amdgcn_mfma_f32_32x32x16_f16(g3, b10, c0_10, 0, 0, 0);
            c0_11 = __builtin_amdgcn_mfma_f32_32x32x16_f16(g3, b11, c0_11, 0, 0, 0);
            __builtin_amdgcn_s_setprio(0);
            b00 = LD8(bb1 + ro0); b01 = LD8(bb1 + ro0 + 2048);
            b10 = LD8(bb1 + ro1); b11 = LD8(bb1 + ro1 + 2048);
            __builtin_amdgcn_s_setprio(1);
            c1_00 = __builtin_amdgcn_mfma_f32_32x32x16_f16(gA, b00, c1_00, 0, 0, 0);
            c1_01 = __builtin_amdgcn_mfma_f32_32x32x16_f16(gA, b01, c1_01, 0, 0, 0);
            c1_10 = __builtin_amdgcn_mfma_f32_32x32x16_f16(gB, b00, c1_10, 0, 0, 0);
            c1_11 = __builtin_amdgcn_mfma_f32_32x32x16_f16(gB, b01, c1_11, 0, 0, 0);
            c1_00 = __builtin_amdgcn_mfma_f32_32x32x16_f16(gC, b10, c1_00, 0, 0, 0);
            c1_01 = __builtin_amdgcn_mfma_f32_32x32x16_f16(gC, b11, c1_01, 0, 0, 0);
            c1_10 = __builtin_amdgcn_mfma_f32_32x32x16_f16(gD, b10, c1_10, 0, 0, 0);
            c1_11 = __builtin_amdgcn_mfma_f32_32x32x16_f16(gD, b11, c1_11, 0, 0, 0);
            __builtin_amdgcn_s_setprio(0);
            b00 = LD8(bb1 + ro2); b01 = LD8(bb1 + ro2 + 2048);
            b10 = LD8(bb1 + ro3); b11 = LD8(bb1 + ro3 + 2048);
            __builtin_amdgcn_s_setprio(1);
            c1_00 = __builtin_amdgcn_mfma_f32_32x32x16_f16(g0, b00, c1_00, 0, 0, 0);
            c1_01 = __builtin_amdgcn_mfma_f32_32x32x16_f16(g0, b01, c1_01, 0, 0, 0);
            c1_10 = __builtin_amdgcn_mfma_f32_32x32x16_f16(g1, b00, c1_10, 0, 0, 0);
            c1_11 = __builtin_amdgcn_mfma_f32_32x32x16_f16(g1, b01, c1_11, 0, 0, 0);
            c1_00 = __builtin_amdgcn_mfma_f32_32x32x16_f16(g2, b10, c1_00, 0, 0, 0);
            c1_01 = __builtin_amdgcn_mfma_f32_32x32x16_f16(g2, b11, c1_01, 0, 0, 0);
            c1_10 = __builtin_amdgcn_mfma_f32_32x32x16_f16(g3, b10, c1_10, 0, 0, 0);
            c1_11 = __builtin_amdgcn_mfma_f32_32x32x16_f16(g3, b11, c1_11, 0, 0, 0);
            __builtin_amdgcn_s_setprio(0);
        }
    }

    // epilogue per n: C/D layout col=lane&31, row=(reg&3)+8*(reg>>2)+4*(lane>>5)
    auto epi = [&](int n, const floatx16& av00, const floatx16& av01,
                   const floatx16& av10, const floatx16& av11) {
        if (EMODE == 3) {
            const int rrb = mt * 64 + wv * 16;
            #pragma unroll
            for (int mi = 0; mi < 2; ++mi) {
                #pragma unroll
                for (int ci = 0; ci < 2; ++ci) {
                    const floatx16& av = mi ? (ci ? av11 : av10) : (ci ? av01 : av00);
                    const int pxe = nt * 64 + ci * 32 + l31;
                    #pragma unroll
                    for (int tq = 0; tq < 4; ++tq) {
                        int rr = rrb + mi * 8 + 2 * tq + hl;
                        size_t gb = ((size_t)n * 1024 + 4 * rr) * kQ + pxe;
                        float iv = av[4 * tq + 0] + pf[gb]          + bias[rr];
                        float fv = av[4 * tq + 1] + pf[gb + kQ]     + bias[256 + rr];
                        float gv = av[4 * tq + 2] + pf[gb + 2 * kQ] + bias[512 + rr];
                        float ov = av[4 * tq + 3] + pf[gb + 3 * kQ] + bias[768 + rr];
                        float cc = sigm(fv) * c0p[((size_t)n * 256 + rr) * kQ + pxe]
                                 + sigm(iv) * tanh_f(gv);
                        float hh = sigm(ov) * tanh_f(cc);
                        h16o[((size_t)n * kQ + pxe) * 256 + rr] = (_Float16)hh;
                    }
                }
            }
            return;
        }
        const int mb0 = mt * 256 + wv * 64;
        #pragma unroll
        for (int mi = 0; mi < 2; ++mi) {
            #pragma unroll
            for (int ci = 0; ci < 2; ++ci) {
                const floatx16& av = mi ? (ci ? av11 : av10) : (ci ? av01 : av00);
                const int pxe = nt * 64 + ci * 32 + l31;
                #pragma unroll
                for (int r = 0; r < 16; ++r) {
                    int rowi = (r & 3) + 8 * (r >> 2) + 4 * hl;
                    int m = mb0 + mi * 32 + rowi;
                    float val = av[r];
                    if (EMODE == 0) {
                        if (m < 256) {
                            q16[((size_t)n * 256 + m) * kQ + pxe] = (_Float16)val;
                        } else if (m < 768) {
                            int ch = m & 255;
                            int yy = pxe / kHW, xx = pxe - yy * kHW;
                            if (yy >= 1 && yy <= 22 && xx >= 1 && xx <= 22) {
                                int d = (yy - 1) * 22 + (xx - 1);
                                int head = n * 8 + (ch >> 5);
                                if (m < 512)
                                    k16[((size_t)head * kDP + d) * 32 + (ch & 31)] = (_Float16)val;
                                else
                                    v16[((size_t)head * 32 + (ch & 31)) * kDP + d] = (_Float16)(val + bias[ch]);
                            }
                        } else {
                            pf[((size_t)n * 1024 + (m - 768)) * kQ + pxe] = val;
                        }
                    } else {
                        pf[((size_t)n * 256 + m) * kQ + pxe] = val + bias[m];
                    }
                }
            }
        }
    };
    epi(n0,     c0_00, c0_01, c0_10, c0_11);
    epi(n0 + 1, c1_00, c1_01, c1_10, c1_11);
}

// ---------------- MFMA flash attention ----------------
__global__ __launch_bounds__(128)
void attn_kernel(const _Float16* __restrict__ q16c, const _Float16* __restrict__ kT16,
                 const _Float16* __restrict__ vC16, _Float16* __restrict__ a16) {
    const int lane = threadIdx.x & 63;
    const int wv   = threadIdx.x >> 6;
    const int l31 = lane & 31, hl = lane >> 5;
    // XCD-chunked swizzle (1152 blocks, 144/XCD): same-head blocks stay on one XCD
    const int lid = blockIdx.x + 9 * blockIdx.y;
    const int swz = (lid & 7) * 144 + (lid >> 3);
    const int bx = swz % 9, head = swz / 9;     // head = n*8 + hd
    const int n = head >> 3, hd = head & 7;
    const int qt = bx * 2 + wv;                 // 0..17
    const int q0 = qt * 32;

    half8 qf0, qf1;
    {
        const _Float16* qb = q16c + ((size_t)n * 256 + hd * 32 + hl * 8) * kQ + q0 + l31;
        #pragma unroll
        for (int j = 0; j < 8; ++j) {
            qf0[j] = qb[(size_t)j * kQ];
            qf1[j] = qb[(size_t)(16 + j) * kQ];
        }
    }

    const _Float16* kbase0 = kT16 + ((size_t)head * kDP + l31) * 32 + hl * 8;
    const _Float16* vbase0 = vC16 + ((size_t)head * 32 + l31) * kDP + hl * 8;

    floatx16 acc = {};
    float m_run = -1e30f, l_run = 0.f;

    half8 kf0 = LD8(kbase0);
    half8 kf1 = LD8(kbase0 + 16);

    for (int dt = 0; dt < 16; ++dt) {
        const int d0 = dt * 32;
        floatx16 S = {};
        S = __builtin_amdgcn_mfma_f32_32x32x16_f16(kf0, qf0, S, 0, 0, 0);
        S = __builtin_amdgcn_mfma_f32_32x32x16_f16(kf1, qf1, S, 0, 0, 0);

        half8 vf0 = LD8(vbase0 + d0);
        half8 vf1 = LD8(vbase0 + d0 + 16);
        if (dt < 15) {
            kf0 = LD8(kbase0 + (size_t)(d0 + 32) * 32);
            kf1 = LD8(kbase0 + (size_t)(d0 + 32) * 32 + 16);
        }

        if (dt == 15) {
            #pragma unroll
            for (int r = 0; r < 16; ++r)
                if (!(hl == 0 && r < 4)) S[r] = -1e30f;
        }

        float tmax = S[0];
        #pragma unroll
        for (int r = 1; r < 16; ++r) tmax = fmaxf(tmax, S[r]);
        tmax = fmaxf(tmax, __shfl_xor(tmax, 32));
        float mnew = fmaxf(m_run, tmax);
        float f = __expf(m_run - mnew);
        float p[16], psum = 0.f;
        #pragma unroll
        for (int r = 0; r < 16; ++r) { p[r] = __expf(S[r] - mnew); psum += p[r]; }
        psum += __shfl_xor(psum, 32);
        l_run = f * l_run + psum;
        #pragma unroll
        for (int r = 0; r < 16; ++r) acc[r] *= f;
        m_run = mnew;

        float other[16];
        #pragma unroll
        for (int r = 0; r < 16; ++r) other[r] = __shfl_xor(p[r], 32);
        half8 pf0, pf1;
        #pragma unroll
        for (int t = 0; t < 4; ++t) {
            pf0[t]     = (_Float16)(hl ? other[4 + t]  : p[t]);
            pf0[4 + t] = (_Float16)(hl ? p[4 + t]      : other[t]);
            pf1[t]     = (_Float16)(hl ? other[12 + t] : p[8 + t]);
            pf1[4 + t] = (_Float16)(hl ? p[12 + t]     : other[8 + t]);
        }

        acc = __builtin_amdgcn_mfma_f32_32x32x16_f16(vf0, pf0, acc, 0, 0, 0);
        acc = __builtin_amdgcn_mfma_f32_32x32x16_f16(vf1, pf1, acc, 0, 0, 0);
    }

    float inv = 1.f / l_run;
    _Float16* ap = a16 + ((size_t)n * kQ + q0 + l31) * 256 + hd * 32;
    #pragma unroll
    for (int r = 0; r < 16; ++r) {
        int c = (r & 3) + 8 * (r >> 2) + 4 * hl;
        ap[c] = (_Float16)(acc[r] * inv);
    }
}

extern "C" void kernel_launch(void* const* d_in, const int* in_sizes, int n_in,
                              void* d_out, int out_size, void* d_ws, size_t ws_size,
                              hipStream_t stream) {
    (void)in_sizes; (void)n_in; (void)out_size; (void)ws_size;
    const float* x     = (const float*)d_in[0];
    const float* h0    = (const float*)d_in[1];
    const float* c0    = (const float*)d_in[2];
    const float* w_in  = (const float*)d_in[3];
    const float* b_in  = (const float*)d_in[4];
    const float* wq_x  = (const float*)d_in[5];
    const float* wq_h  = (const float*)d_in[6];
    const float* wk_x  = (const float*)d_in[7];
    const float* wk_h  = (const float*)d_in[8];
    const float* wv_x  = (const float*)d_in[9];
    const float* wv_h  = (const float*)d_in[10];
    const float* bv    = (const float*)d_in[11];
    const float* wg_a  = (const float*)d_in[12];
    const float* bg    = (const float*)d_in[13];
    const float* wg_x  = (const float*)d_in[14];
    const float* wg_h  = (const float*)d_in[15];
    const float* w_out = (const float*)d_in[16];
    const float* b_out = (const float*)d_in[17];

    _Float16* wh = (_Float16*)d_ws;
    _Float16* xpad16  = wh + H_XPAD;
    _Float16* hpad16  = wh + H_HPAD;
    _Float16* apack1  = wh + H_APACK1;
    _Float16* apack2  = wh + H_APACK2;
    _Float16* apack3  = wh + H_APACK3;
    _Float16* a16     = wh + H_A16;
    _Float16* h16     = wh + H_H16;
    _Float16* q16c    = wh + H_Q16C;
    _Float16* kT16    = wh + H_KT16;
    _Float16* vC16    = wh + H_VC16;
    float* gbuf = (float*)((char*)d_ws + HALF_BYTES) + F_G;

    // zero NHWC image borders (ws re-poisoned each launch)
    hipMemsetAsync(wh, 0, 11075584, stream);

    // weight packing (fragment-order BK=64 tiles; gate rows interleaved)
    pack1_kernel<<<896, 256, 0, stream>>>(wq_x, wq_h, wk_x, wk_h, wv_x, wv_h, wg_x, wg_h, apack1);
    pack_flat_kernel<1><<<128, 256, 0, stream>>>(wg_a, apack2, 256, kKT2);
    pack_flat_kernel<0><<<32, 256, 0, stream>>>(w_out, apack3, 256, kKT3);

    // input staging (NHWC fp16)
    pad_nhwc_kernel<<<dim3(9, 8, kN), 256, 0, stream>>>(h0, hpad16);
    conv1x1_pad_kernel<<<dim3(9, 16, kN), dim3(64, 4), 0, stream>>>(x, w_in, b_in, xpad16);

    // fused q/k/v/gates3x3 GEMM: M=1792, K=4608, N=576 x 16 batches (n-pairs)
    gemm_kernel<0, 0><<<dim3(9, 8, 7), 256, 0, stream>>>(
        apack1, xpad16, hpad16, q16c, kT16, vC16, gbuf, bv, nullptr, nullptr, kKT1, 0);

    // MFMA flash attention -> a16 [n][px][256]
    attn_kernel<<<dim3(9, 128), 128, 0, stream>>>(q16c, kT16, vC16, a16);

    // gates = wg_a . a + bg + gbuf, fused LSTM -> h16 [n][px][256]
    gemm_kernel<1, 3><<<dim3(9, 8, 4), 256, 0, stream>>>(
        apack2, a16, nullptr, nullptr, nullptr, nullptr, gbuf, bg, c0, h16, kKT2, 256);

    // out = w_out . h + b_out : M=256 -> 1 m-tile
    gemm_kernel<1, 2><<<dim3(9, 8, 1), 256, 0, stream>>>(
        apack3, h16, nullptr, nullptr, nullptr, nullptr, (float*)d_out, b_out, nullptr, nullptr, kKT3, 256);
}

// Round 9
// 389.947 us; speedup vs baseline: 1.0453x; 1.0264x over previous
//
#include <hip/hip_runtime.h>
#include <cstddef>

// ---- problem constants ----
constexpr int kN  = 16;
constexpr int kI  = 128;
constexpr int kHW = 24;
constexpr int kQ  = 576;    // 24*24
constexpr int kD  = 484;    // 22*22
constexpr int kDP = 512;    // padded d
constexpr int kPP = 676;    // 26*26 padded

// GEMM K-tiling (BK=64)
constexpr int kKT1 = 72;    // K1 = 4608 / 64
constexpr int kKT2 = 4;     // K2 = 256 / 64
constexpr int kKT3 = 4;     // K3 = 256 / 64

// ---- workspace layout ----
// half region (element offsets into _Float16*)
constexpr size_t H_XPAD   = 0;                          // [16][26][26][256] NHWC
constexpr size_t H_HPAD   = 2768896;                    // [16][26][26][256] NHWC
constexpr size_t H_APACK1 = 5537792;                    // 1792*4608 frag-tiled (256-row, BK64)
constexpr size_t H_APACK2 = 13795328;                   // 1024*256 frag-tiled
constexpr size_t H_APACK3 = 14057472;                   // 256*256 frag-tiled
constexpr size_t H_A16    = 14123008;                   // [16][576][256]
constexpr size_t H_H16    = 16482304;                   // [16][576][256]
constexpr size_t H_Q16C   = 18841600;                   // [16][256][576]  (c-major)
constexpr size_t H_KT16   = 21200896;                   // [128 head][512 d][32 c]
constexpr size_t H_VC16   = 23298048;                   // [128 head][32 c][512 d]
constexpr size_t HALF_ELEMS = 25395200;
constexpr size_t HALF_BYTES = HALF_ELEMS * 2;           // 50,790,400
// float region at d_ws + HALF_BYTES
constexpr size_t F_G = 0;                               // [16][1024][576]

constexpr size_t kXHGap = H_HPAD - H_XPAD;              // hpad - xpad element gap

using half8    = __attribute__((ext_vector_type(8))) _Float16;
using floatx16 = __attribute__((ext_vector_type(16))) float;

__device__ __forceinline__ float sigm(float x) { return 1.0f / (1.0f + __expf(-x)); }
__device__ __forceinline__ float tanh_f(float x) {
    float e = __expf(2.0f * fabsf(x));
    float r = 1.0f - 2.0f / (e + 1.0f);
    return copysignf(r, x);
}

// 16B-aligned vector load/store (emits b128 ops)
__device__ __forceinline__ half8 LD8(const _Float16* p) { return *(const half8*)p; }
__device__ __forceinline__ void ST8(_Float16* p, half8 v) { *(half8*)p = v; }

// ---------------- fused staging kernel ----------------
// R9 (= R8 with conv block-range bug fixed): fuse ALL independent staging ops
// into ONE kernel. 9 dispatches -> 5. Block roles:
//   [0,896)      pack1: coalesced LDS-transpose of 3x3 weights -> apack1
//   [896,1024)   pack_flat PERM=1: wg_a -> apack2 (gate-interleaved rows)
//   [1024,1056)  pack_flat PERM=0: w_out -> apack3
//   [1056,2208)  pad_nhwc: h0 fp32 NCHW -> hpad16 NHWC interior (1152 blocks)
//   [2208,4512)  conv1x1: xin = w_in.x + b_in -> xpad16 interior (2304 blocks,
//                R8 BUG: had 144 blocks, n was always 0 -> 15/16 of xpad unwritten)
//   [4512,4544)  border zero: 100-px frame of each (img, n) image
// All roles write disjoint addresses. Shared LDS = 36 KB union.
__global__ __launch_bounds__(256)
void staging_kernel(const float* __restrict__ wq_x, const float* __restrict__ wq_h,
                    const float* __restrict__ wk_x, const float* __restrict__ wk_h,
                    const float* __restrict__ wv_x, const float* __restrict__ wv_h,
                    const float* __restrict__ wg_x, const float* __restrict__ wg_h,
                    const float* __restrict__ wg_a, const float* __restrict__ w_out,
                    const float* __restrict__ h0, const float* __restrict__ x,
                    const float* __restrict__ w_in, const float* __restrict__ b_in,
                    _Float16* __restrict__ apack1, _Float16* __restrict__ apack2,
                    _Float16* __restrict__ apack3, _Float16* __restrict__ xpad16,
                    _Float16* __restrict__ hpad16) {
    __shared__ float ls[9216];                 // 36 KB union (pack1 / pad tile)
    const int b = blockIdx.x;
    const int tid = threadIdx.x;

    if (b < 896) {
        // ---- pack1: [mt][kt][kk4][hl2][row256][j8], coalesced LDS-transpose ----
        // K-order: k = src*2304 + tap*256 + ic. Gate rows (mt>=3) interleaved
        // m' = 4*r + gate for the fused LSTM epilogue.
        const int rg   = b & 15;
        const int icb  = (b >> 4) & 3;
        const int srcs = (b >> 6) & 1;
        const int mt   = b >> 7;
        const float *s1, *s2;
        if (mt == 0)      { s1 = wq_x; s2 = wq_h; }
        else if (mt == 1) { s1 = wk_x; s2 = wk_h; }
        else if (mt == 2) { s1 = wv_x; s2 = wv_h; }
        else              { s1 = wg_x; s2 = wg_h; }
        const float* sp = srcs ? s2 : s1;
        #pragma unroll
        for (int rep = 0; rep < 36; ++rep) {
            int f = rep * 256 + tid;
            int row = f / 576, off = f - row * 576;
            int mm;
            if (mt < 3) {
                mm = rg * 16 + row;
            } else {
                int mp = (mt - 3) * 256 + rg * 16 + row;     // m - 768
                mm = (mp & 3) * 256 + (mp >> 2);             // gate interleave
            }
            ls[f] = sp[(size_t)mm * 2304 + (size_t)icb * 576 + off];
        }
        __syncthreads();
        const size_t mt_base = (size_t)mt * 72 * 16384;
        for (int c = tid; c < 1152; c += 256) {
            int row = c / 72, rem = c - row * 72;
            int tap = rem >> 3, khl = rem & 7;
            int kk = khl >> 1, hl = khl & 1;
            int kt = srcs * 36 + tap * 4 + icb;
            const float* lp = ls + row * 576 + (kk * 16 + hl * 8) * 9 + tap;
            half8 v;
            #pragma unroll
            for (int j = 0; j < 8; ++j) v[j] = (_Float16)lp[j * 9];
            ST8(apack1 + mt_base + (size_t)kt * 16384 + kk * 4096 + hl * 2048
                    + (size_t)(rg * 16 + row) * 8, v);
        }
    } else if (b < 1056) {
        // ---- pack_flat: wg_a (PERM=1, 128 blks) / w_out (PERM=0, 32 blks) ----
        const int perm = (b < 1024) ? 1 : 0;
        const float* src = perm ? wg_a : w_out;
        _Float16* dst = perm ? apack2 : apack3;
        int p8 = (b - (perm ? 896 : 1024)) * 256 + tid;
        int row = p8 & 255, hl = (p8 >> 8) & 1, kk = (p8 >> 9) & 3;
        int tile = p8 >> 11;
        int mt = tile >> 2, kt = tile & 3;                 // Ktiles = 4
        int m = mt * 256 + row;
        int k0 = kt * 64 + kk * 16 + hl * 8;
        int mm = perm ? ((m & 3) * 256 + (m >> 2)) : m;
        const float* sp = src + (size_t)mm * 256 + k0;
        half8 v;
        #pragma unroll
        for (int j = 0; j < 8; ++j) v[j] = (_Float16)sp[j];
        ST8(dst + (size_t)p8 * 8, v);
    } else if (b < 2208) {
        // ---- pad_nhwc: h0 [n][256][576] fp32 -> hpad16 NHWC interior ----
        float (*tile)[65] = (float(*)[65])ls;              // 32x65 floats
        const int bb = b - 1056;
        const int pxt = bb % 9, ict = (bb / 9) & 7, n = bb / 72;
        {
            int icl = tid >> 6, pxl = tid & 63;
            #pragma unroll
            for (int rep = 0; rep < 8; ++rep) {
                int ic = ict * 32 + rep * 4 + icl;
                tile[rep * 4 + icl][pxl] = h0[((size_t)n * 256 + ic) * kQ + pxt * 64 + pxl];
            }
        }
        __syncthreads();
        {
            int icl = tid & 31, pxl0 = tid >> 5;
            #pragma unroll
            for (int rep = 0; rep < 8; ++rep) {
                int pxl = rep * 8 + pxl0;
                int px = pxt * 64 + pxl;
                int y = px / kHW, xx = px - y * kHW;
                hpad16[((size_t)n * kPP + (size_t)(y + 1) * 26 + (xx + 1)) * 256 + ict * 32 + icl] =
                    (_Float16)tile[icl][pxl];
            }
        }
    } else if (b < 4512) {
        // ---- conv1x1: xin = w_in . x + b_in -> xpad16 NHWC interior ----
        // 2304 blocks = 9 px-tiles x 16 oc-tiles x 16 n
        const int bb = b - 2208;
        const int bx = bb % 9, by = (bb / 9) & 15, n = bb / 144;
        const int tx = tid & 63, ty = tid >> 6;
        int px = bx * 64 + tx;
        int oc0 = __builtin_amdgcn_readfirstlane(by * 16 + ty * 4);
        const float* ip = x + (size_t)n * kI * kQ + px;
        float acc[4] = {0.f, 0.f, 0.f, 0.f};
        #pragma unroll 4
        for (int ic = 0; ic < kI; ++ic) {
            float xv = ip[(size_t)ic * kQ];
            #pragma unroll
            for (int j = 0; j < 4; ++j) acc[j] = fmaf(xv, w_in[(size_t)(oc0 + j) * kI + ic], acc[j]);
        }
        int y = px / kHW, xc = px - y * kHW;
        _Float16* op = xpad16 + ((size_t)n * kPP + (size_t)(y + 1) * 26 + (xc + 1)) * 256 + oc0;
        #pragma unroll
        for (int j = 0; j < 4; ++j) op[j] = (_Float16)(acc[j] + b_in[oc0 + j]);
    } else {
        // ---- border zero: 100-px frame of one (img, n) image ----
        const int bb = b - 4512;
        _Float16* img = (bb >> 4) ? hpad16 : xpad16;
        const int n = bb & 15;
        _Float16* base = img + (size_t)n * kPP * 256;
        #pragma unroll 4
        for (int rep = 0; rep < 100; ++rep) {
            int y, xx;
            if (rep < 26)      { y = 0;        xx = rep; }
            else if (rep < 52) { y = 25;       xx = rep - 26; }
            else if (rep < 76) { y = rep - 51; xx = 0; }       // y = 1..24
            else               { y = rep - 75; xx = 25; }      // y = 1..24
            base[((size_t)y * 26 + xx) * 256 + tid] = (_Float16)0.f;
        }
    }
}

// ---------------- fused MFMA GEMM (BK=64, batch-pair) — frozen from R7 ----------------
// Each block computes TWO n-batches with ONE A read (VMEM-byte bound fix, R7:
// FETCH 128->79 MB, 187->167 µs). Grid 504 @ 2 blocks/CU, single round.
// BM=256, BN=64x2n, BK=64; 4 waves; 8 accs/wave; raw s_barrier + lgkmcnt(0);
// counted vmcnt prefetches (R4); setprio around MFMA clusters.
template<int BMODE, int EMODE>
__global__ __launch_bounds__(256, 2)
void gemm_kernel(const _Float16* __restrict__ Apack,
                 const _Float16* __restrict__ B1, const _Float16* __restrict__ B2,
                 _Float16* __restrict__ q16, _Float16* __restrict__ k16,
                 _Float16* __restrict__ v16, float* __restrict__ pf,
                 const float* __restrict__ bias, const float* __restrict__ c0p,
                 _Float16* __restrict__ h16o, int Ktiles, int Ktot) {
    __shared__ _Float16 Bs[2][2][4096];        // [dbuf][nidx][64px*64k]
    const int tid = threadIdx.x;
    const int wv = tid >> 6, lane = tid & 63, l31 = lane & 31, hl = lane >> 5;
    const int nt = blockIdx.x, np = blockIdx.y, mt = blockIdx.z;
    const int n0 = np * 2;

    floatx16 c0_00 = {}, c0_01 = {}, c0_10 = {}, c0_11 = {};   // n0: mi,ci
    floatx16 c1_00 = {}, c1_01 = {}, c1_10 = {}, c1_11 = {};   // n1

    const _Float16* abase = Apack + (size_t)mt * Ktiles * 16384;
    const int aoff = hl * 2048 + (wv * 64 + l31) * 8;

    const int px_l = tid >> 2, bc = tid & 3;
    const int px = nt * 64 + px_l;
    const int by = px / kHW, bx = px - by * kHW;

    const int sw = px_l & 7;
    const int wofs0 = px_l * 64 + (((2 * bc) ^ sw) << 3);
    const int wofs1 = px_l * 64 + (((2 * bc + 1) ^ sw) << 3);
    const int rsw = l31 & 7;
    const int ro0 = l31 * 64 + (((0 + hl) ^ rsw) << 3);    // kkc0; +2048 for ci=1
    const int ro1 = l31 * 64 + (((2 + hl) ^ rsw) << 3);
    const int ro2 = l31 * 64 + (((4 + hl) ^ rsw) << 3);
    const int ro3 = l31 * 64 + (((6 + hl) ^ rsw) << 3);

    const _Float16 *bsx0, *bsx1;
    if (BMODE == 0) {
        bsx0 = B1 + ((size_t)n0 * kPP + (size_t)by * 26 + bx) * 256 + (size_t)bc * 16;
        bsx1 = bsx0 + (size_t)kPP * 256;
    } else {
        bsx0 = B1 + ((size_t)n0 * kQ + px) * Ktot + bc * 16;
        bsx1 = bsx0 + (size_t)kQ * Ktot;
    }

    auto loadB = [&](const _Float16* base, int kt, half8& lo, half8& hi) {
        if (BMODE == 0) {
            int srcs = (kt >= 36) ? 1 : 0;
            int ktl = kt - srcs * 36;
            int tap = ktl >> 2, icb = (ktl & 3) << 6;
            int ty = (tap * 11) >> 5;          // tap/3 for 0..9
            int tx = tap - ty * 3;
            const _Float16* p = base + (size_t)srcs * kXHGap
                              + ((size_t)(ty * 26 + tx)) * 256 + icb;
            lo = LD8(p); hi = LD8(p + 8);
        } else {
            const _Float16* p = base + kt * 64;
            lo = LD8(p); hi = LD8(p + 8);
        }
    };

    half8 e0l, e0h, e1l, e1h, o0l, o0h, o1l, o1h;
    loadB(bsx0, 0, e0l, e0h); loadB(bsx1, 0, e1l, e1h);
    loadB(bsx0, 1, o0l, o0h); loadB(bsx1, 1, o1l, o1h);

    for (int kt = 0; kt < Ktiles; kt += 2) {
        const _Float16* ab = abase + (size_t)kt * 16384;
        // ================= even step: buffer 0 = tile kt =================
        ST8(&Bs[0][0][wofs0], e0l); ST8(&Bs[0][0][wofs1], e0h);
        ST8(&Bs[0][1][wofs0], e1l); ST8(&Bs[0][1][wofs1], e1h);
        half8 aA = LD8(ab + aoff),          aB = LD8(ab + aoff + 256);          // kkc0
        half8 aC = LD8(ab + 4096 + aoff),   aD = LD8(ab + 4096 + aoff + 256);   // kkc1
        half8 f0 = LD8(ab + 8192 + aoff),   f1 = LD8(ab + 8192 + aoff + 256);   // kkc2
        half8 f2 = LD8(ab + 12288 + aoff),  f3 = LD8(ab + 12288 + aoff + 256);  // kkc3
        loadB(bsx0, kt + 2, e0l, e0h); loadB(bsx1, kt + 2, e1l, e1h);           // 2-deep B
        asm volatile("s_waitcnt lgkmcnt(0)" ::: "memory");
        __builtin_amdgcn_s_barrier();
        {
            const _Float16* bb0 = Bs[0][0];
            const _Float16* bb1 = Bs[0][1];
            half8 b00 = LD8(bb0 + ro0), b01 = LD8(bb0 + ro0 + 2048);
            half8 b10 = LD8(bb0 + ro1), b11 = LD8(bb0 + ro1 + 2048);
            __builtin_amdgcn_s_setprio(1);
            c0_00 = __builtin_amdgcn_mfma_f32_32x32x16_f16(aA, b00, c0_00, 0, 0, 0);
            c0_01 = __builtin_amdgcn_mfma_f32_32x32x16_f16(aA, b01, c0_01, 0, 0, 0);
            c0_10 = __builtin_amdgcn_mfma_f32_32x32x16_f16(aB, b00, c0_10, 0, 0, 0);
            c0_11 = __builtin_amdgcn_mfma_f32_32x32x16_f16(aB, b01, c0_11, 0, 0, 0);
            c0_00 = __builtin_amdgcn_mfma_f32_32x32x16_f16(aC, b10, c0_00, 0, 0, 0);
            c0_01 = __builtin_amdgcn_mfma_f32_32x32x16_f16(aC, b11, c0_01, 0, 0, 0);
            c0_10 = __builtin_amdgcn_mfma_f32_32x32x16_f16(aD, b10, c0_10, 0, 0, 0);
            c0_11 = __builtin_amdgcn_mfma_f32_32x32x16_f16(aD, b11, c0_11, 0, 0, 0);
            __builtin_amdgcn_s_setprio(0);
            b00 = LD8(bb0 + ro2); b01 = LD8(bb0 + ro2 + 2048);
            b10 = LD8(bb0 + ro3); b11 = LD8(bb0 + ro3 + 2048);
            __builtin_amdgcn_s_setprio(1);
            c0_00 = __builtin_amdgcn_mfma_f32_32x32x16_f16(f0, b00, c0_00, 0, 0, 0);
            c0_01 = __builtin_amdgcn_mfma_f32_32x32x16_f16(f0, b01, c0_01, 0, 0, 0);
            c0_10 = __builtin_amdgcn_mfma_f32_32x32x16_f16(f1, b00, c0_10, 0, 0, 0);
            c0_11 = __builtin_amdgcn_mfma_f32_32x32x16_f16(f1, b01, c0_11, 0, 0, 0);
            c0_00 = __builtin_amdgcn_mfma_f32_32x32x16_f16(f2, b10, c0_00, 0, 0, 0);
            c0_01 = __builtin_amdgcn_mfma_f32_32x32x16_f16(f2, b11, c0_01, 0, 0, 0);
            c0_10 = __builtin_amdgcn_mfma_f32_32x32x16_f16(f3, b10, c0_10, 0, 0, 0);
            c0_11 = __builtin_amdgcn_mfma_f32_32x32x16_f16(f3, b11, c0_11, 0, 0, 0);
            __builtin_amdgcn_s_setprio(0);
            b00 = LD8(bb1 + ro0); b01 = LD8(bb1 + ro0 + 2048);
            b10 = LD8(bb1 + ro1); b11 = LD8(bb1 + ro1 + 2048);
            __builtin_amdgcn_s_setprio(1);
            c1_00 = __builtin_amdgcn_mfma_f32_32x32x16_f16(aA, b00, c1_00, 0, 0, 0);
            c1_01 = __builtin_amdgcn_mfma_f32_32x32x16_f16(aA, b01, c1_01, 0, 0, 0);
            c1_10 = __builtin_amdgcn_mfma_f32_32x32x16_f16(aB, b00, c1_10, 0, 0, 0);
            c1_11 = __builtin_amdgcn_mfma_f32_32x32x16_f16(aB, b01, c1_11, 0, 0, 0);
            c1_00 = __builtin_amdgcn_mfma_f32_32x32x16_f16(aC, b10, c1_00, 0, 0, 0);
            c1_01 = __builtin_amdgcn_mfma_f32_32x32x16_f16(aC, b11, c1_01, 0, 0, 0);
            c1_10 = __builtin_amdgcn_mfma_f32_32x32x16_f16(aD, b10, c1_10, 0, 0, 0);
            c1_11 = __builtin_amdgcn_mfma_f32_32x32x16_f16(aD, b11, c1_11, 0, 0, 0);
            __builtin_amdgcn_s_setprio(0);
            b00 = LD8(bb1 + ro2); b01 = LD8(bb1 + ro2 + 2048);
            b10 = LD8(bb1 + ro3); b11 = LD8(bb1 + ro3 + 2048);
            __builtin_amdgcn_s_setprio(1);
            c1_00 = __builtin_amdgcn_mfma_f32_32x32x16_f16(f0, b00, c1_00, 0, 0, 0);
            c1_01 = __builtin_amdgcn_mfma_f32_32x32x16_f16(f0, b01, c1_01, 0, 0, 0);
            c1_10 = __builtin_amdgcn_mfma_f32_32x32x16_f16(f1, b00, c1_10, 0, 0, 0);
            c1_11 = __builtin_amdgcn_mfma_f32_32x32x16_f16(f1, b01, c1_11, 0, 0, 0);
            c1_00 = __builtin_amdgcn_mfma_f32_32x32x16_f16(f2, b10, c1_00, 0, 0, 0);
            c1_01 = __builtin_amdgcn_mfma_f32_32x32x16_f16(f2, b11, c1_01, 0, 0, 0);
            c1_10 = __builtin_amdgcn_mfma_f32_32x32x16_f16(f3, b10, c1_10, 0, 0, 0);
            c1_11 = __builtin_amdgcn_mfma_f32_32x32x16_f16(f3, b11, c1_11, 0, 0, 0);
            __builtin_amdgcn_s_setprio(0);
        }
        // ================= odd step: buffer 1 = tile kt+1 =================
        const _Float16* ab2 = ab + 16384;
        ST8(&Bs[1][0][wofs0], o0l); ST8(&Bs[1][0][wofs1], o0h);
        ST8(&Bs[1][1][wofs0], o1l); ST8(&Bs[1][1][wofs1], o1h);
        half8 gA = LD8(ab2 + aoff),          gB = LD8(ab2 + aoff + 256);
        half8 gC = LD8(ab2 + 4096 + aoff),   gD = LD8(ab2 + 4096 + aoff + 256);
        half8 g0 = LD8(ab2 + 8192 + aoff),   g1 = LD8(ab2 + 8192 + aoff + 256);
        half8 g2 = LD8(ab2 + 12288 + aoff),  g3 = LD8(ab2 + 12288 + aoff + 256);
        loadB(bsx0, kt + 3, o0l, o0h); loadB(bsx1, kt + 3, o1l, o1h);
        asm volatile("s_waitcnt lgkmcnt(0)" ::: "memory");
        __builtin_amdgcn_s_barrier();
        {
            const _Float16* bb0 = Bs[1][0];
            const _Float16* bb1 = Bs[1][1];
            half8 b00 = LD8(bb0 + ro0), b01 = LD8(bb0 + ro0 + 2048);
            half8 b10 = LD8(bb0 + ro1), b11 = LD8(bb0 + ro1 + 2048);
            __builtin_amdgcn_s_setprio(1);
            c0_00 = __builtin_amdgcn_mfma_f32_32x32x16_f16(gA, b00, c0_00, 0, 0, 0);
            c0_01 = __builtin_amdgcn_mfma_f32_32x32x16_f16(gA, b01, c0_01, 0, 0, 0);
            c0_10 = __builtin_amdgcn_mfma_f32_32x32x16_f16(gB, b00, c0_10, 0, 0, 0);
            c0_11 = __builtin_amdgcn_mfma_f32_32x32x16_f16(gB, b01, c0_11, 0, 0, 0);
            c0_00 = __builtin_amdgcn_mfma_f32_32x32x16_f16(gC, b10, c0_00, 0, 0, 0);
            c0_01 = __builtin_amdgcn_mfma_f32_32x32x16_f16(gC, b11, c0_01, 0, 0, 0);
            c0_10 = __builtin_amdgcn_mfma_f32_32x32x16_f16(gD, b10, c0_10, 0, 0, 0);
            c0_11 = __builtin_amdgcn_mfma_f32_32x32x16_f16(gD, b11, c0_11, 0, 0, 0);
            __builtin_amdgcn_s_setprio(0);
            b00 = LD8(bb0 + ro2); b01 = LD8(bb0 + ro2 + 2048);
            b10 = LD8(bb0 + ro3); b11 = LD8(bb0 + ro3 + 2048);
            __builtin_amdgcn_s_setprio(1);
            c0_00 = __builtin_amdgcn_mfma_f32_32x32x16_f16(g0, b00, c0_00, 0, 0, 0);
            c0_01 = __builtin_amdgcn_mfma_f32_32x32x16_f16(g0, b01, c0_01, 0, 0, 0);
            c0_10 = __builtin_amdgcn_mfma_f32_32x32x16_f16(g1, b00, c0_10, 0, 0, 0);
            c0_11 = __builtin_amdgcn_mfma_f32_32x32x16_f16(g1, b01, c0_11, 0, 0, 0);
            c0_00 = __builtin_amdgcn_mfma_f32_32x32x16_f16(g2, b10, c0_00, 0, 0, 0);
            c0_01 = __builtin_amdgcn_mfma_f32_32x32x16_f16(g2, b11, c0_01, 0, 0, 0);
            c0_10 = __builtin_amdgcn_mfma_f32_32x32x16_f16(g3, b10, c0_10, 0, 0, 0);
            c0_11 = __builtin_amdgcn_mfma_f32_32x32x16_f16(g3, b11, c0_11, 0, 0, 0);
            __builtin_amdgcn_s_setprio(0);
            b00 = LD8(bb1 + ro0); b01 = LD8(bb1 + ro0 + 2048);
            b10 = LD8(bb1 + ro1); b11 = LD8(bb1 + ro1 + 2048);
            __builtin_amdgcn_s_setprio(1);
            c1_00 = __builtin_amdgcn_mfma_f32_32x32x16_f16(gA, b00, c1_00, 0, 0, 0);
            c1_01 = __builtin_amdgcn_mfma_f32_32x32x16_f16(gA, b01, c1_01, 0, 0, 0);
            c1_10 = __builtin_amdgcn_mfma_f32_32x32x16_f16(gB, b00, c1_10, 0, 0, 0);
            c1_11 = __builtin_amdgcn_mfma_f32_32x32x16_f16(gB, b01, c1_11, 0, 0, 0);
            c1_00 = __builtin_amdgcn_mfma_f32_32x32x16_f16(gC, b10, c1_00, 0, 0, 0);
            c1_01 = __builtin_amdgcn_mfma_f32_32x32x16_f16(gC, b11, c1_01, 0, 0, 0);
            c1_10 = __builtin_amdgcn_mfma_f32_32x32x16_f16(gD, b10, c1_10, 0, 0, 0);
            c1_11 = __builtin_amdgcn_mfma_f32_32x32x16_f16(gD, b11, c1_11, 0, 0, 0);
            __builtin_amdgcn_s_setprio(0);
            b00 = LD8(bb1 + ro2); b01 = LD8(bb1 + ro2 + 2048);
            b10 = LD8(bb1 + ro3); b11 = LD8(bb1 + ro3 + 2048);
            __builtin_amdgcn_s_setprio(1);
            c1_00 = __builtin_amdgcn_mfma_f32_32x32x16_f16(g0, b00, c1_00, 0, 0, 0);
            c1_01 = __builtin_amdgcn_mfma_f32_32x32x16_f16(g0, b01, c1_01, 0, 0, 0);
            c1_10 = __builtin_amdgcn_mfma_f32_32x32x16_f16(g1, b00, c1_10, 0, 0, 0);
            c1_11 = __builtin_amdgcn_mfma_f32_32x32x16_f16(g1, b01, c1_11, 0, 0, 0);
            c1_00 = __builtin_amdgcn_mfma_f32_32x32x16_f16(g2, b10, c1_00, 0, 0, 0);
            c1_01 = __builtin_amdgcn_mfma_f32_32x32x16_f16(g2, b11, c1_01, 0, 0, 0);
            c1_10 = __builtin_amdgcn_mfma_f32_32x32x16_f16(g3, b10, c1_10, 0, 0, 0);
            c1_11 = __builtin_amdgcn_mfma_f32_32x32x16_f16(g3, b11, c1_11, 0, 0, 0);
            __builtin_amdgcn_s_setprio(0);
        }
    }

    // epilogue per n: C/D layout col=lane&31, row=(reg&3)+8*(reg>>2)+4*(lane>>5)
    auto epi = [&](int n, const floatx16& av00, const floatx16& av01,
                   const floatx16& av10, const floatx16& av11) {
        if (EMODE == 3) {
            const int rrb = mt * 64 + wv * 16;
            #pragma unroll
            for (int mi = 0; mi < 2; ++mi) {
                #pragma unroll
                for (int ci = 0; ci < 2; ++ci) {
                    const floatx16& av = mi ? (ci ? av11 : av10) : (ci ? av01 : av00);
                    const int pxe = nt * 64 + ci * 32 + l31;
                    #pragma unroll
                    for (int tq = 0; tq < 4; ++tq) {
                        int rr = rrb + mi * 8 + 2 * tq + hl;
                        size_t gb = ((size_t)n * 1024 + 4 * rr) * kQ + pxe;
                        float iv = av[4 * tq + 0] + pf[gb]          + bias[rr];
                        float fv = av[4 * tq + 1] + pf[gb + kQ]     + bias[256 + rr];
                        float gv = av[4 * tq + 2] + pf[gb + 2 * kQ] + bias[512 + rr];
                        float ov = av[4 * tq + 3] + pf[gb + 3 * kQ] + bias[768 + rr];
                        float cc = sigm(fv) * c0p[((size_t)n * 256 + rr) * kQ + pxe]
                                 + sigm(iv) * tanh_f(gv);
                        float hh = sigm(ov) * tanh_f(cc);
                        h16o[((size_t)n * kQ + pxe) * 256 + rr] = (_Float16)hh;
                    }
                }
            }
            return;
        }
        const int mb0 = mt * 256 + wv * 64;
        #pragma unroll
        for (int mi = 0; mi < 2; ++mi) {
            #pragma unroll
            for (int ci = 0; ci < 2; ++ci) {
                const floatx16& av = mi ? (ci ? av11 : av10) : (ci ? av01 : av00);
                const int pxe = nt * 64 + ci * 32 + l31;
                #pragma unroll
                for (int r = 0; r < 16; ++r) {
                    int rowi = (r & 3) + 8 * (r >> 2) + 4 * hl;
                    int m = mb0 + mi * 32 + rowi;
                    float val = av[r];
                    if (EMODE == 0) {
                        if (m < 256) {
                            q16[((size_t)n * 256 + m) * kQ + pxe] = (_Float16)val;
                        } else if (m < 768) {
                            int ch = m & 255;
                            int yy = pxe / kHW, xx = pxe - yy * kHW;
                            if (yy >= 1 && yy <= 22 && xx >= 1 && xx <= 22) {
                                int d = (yy - 1) * 22 + (xx - 1);
                                int head = n * 8 + (ch >> 5);
                                if (m < 512)
                                    k16[((size_t)head * kDP + d) * 32 + (ch & 31)] = (_Float16)val;
                                else
                                    v16[((size_t)head * 32 + (ch & 31)) * kDP + d] = (_Float16)(val + bias[ch]);
                            }
                        } else {
                            pf[((size_t)n * 1024 + (m - 768)) * kQ + pxe] = val;
                        }
                    } else {
                        pf[((size_t)n * 256 + m) * kQ + pxe] = val + bias[m];
                    }
                }
            }
        }
    };
    epi(n0,     c0_00, c0_01, c0_10, c0_11);
    epi(n0 + 1, c1_00, c1_01, c1_10, c1_11);
}

// ---------------- MFMA flash attention (frozen) ----------------
__global__ __launch_bounds__(128)
void attn_kernel(const _Float16* __restrict__ q16c, const _Float16* __restrict__ kT16,
                 const _Float16* __restrict__ vC16, _Float16* __restrict__ a16) {
    const int lane = threadIdx.x & 63;
    const int wv   = threadIdx.x >> 6;
    const int l31 = lane & 31, hl = lane >> 5;
    const int lid = blockIdx.x + 9 * blockIdx.y;
    const int swz = (lid & 7) * 144 + (lid >> 3);
    const int bx = swz % 9, head = swz / 9;     // head = n*8 + hd
    const int n = head >> 3, hd = head & 7;
    const int qt = bx * 2 + wv;                 // 0..17
    const int q0 = qt * 32;

    half8 qf0, qf1;
    {
        const _Float16* qb = q16c + ((size_t)n * 256 + hd * 32 + hl * 8) * kQ + q0 + l31;
        #pragma unroll
        for (int j = 0; j < 8; ++j) {
            qf0[j] = qb[(size_t)j * kQ];
            qf1[j] = qb[(size_t)(16 + j) * kQ];
        }
    }

    const _Float16* kbase0 = kT16 + ((size_t)head * kDP + l31) * 32 + hl * 8;
    const _Float16* vbase0 = vC16 + ((size_t)head * 32 + l31) * kDP + hl * 8;

    floatx16 acc = {};
    float m_run = -1e30f, l_run = 0.f;

    half8 kf0 = LD8(kbase0);
    half8 kf1 = LD8(kbase0 + 16);

    for (int dt = 0; dt < 16; ++dt) {
        const int d0 = dt * 32;
        floatx16 S = {};
        S = __builtin_amdgcn_mfma_f32_32x32x16_f16(kf0, qf0, S, 0, 0, 0);
        S = __builtin_amdgcn_mfma_f32_32x32x16_f16(kf1, qf1, S, 0, 0, 0);

        half8 vf0 = LD8(vbase0 + d0);
        half8 vf1 = LD8(vbase0 + d0 + 16);
        if (dt < 15) {
            kf0 = LD8(kbase0 + (size_t)(d0 + 32) * 32);
            kf1 = LD8(kbase0 + (size_t)(d0 + 32) * 32 + 16);
        }

        if (dt == 15) {
            #pragma unroll
            for (int r = 0; r < 16; ++r)
                if (!(hl == 0 && r < 4)) S[r] = -1e30f;
        }

        float tmax = S[0];
        #pragma unroll
        for (int r = 1; r < 16; ++r) tmax = fmaxf(tmax, S[r]);
        tmax = fmaxf(tmax, __shfl_xor(tmax, 32));
        float mnew = fmaxf(m_run, tmax);
        float f = __expf(m_run - mnew);
        float p[16], psum = 0.f;
        #pragma unroll
        for (int r = 0; r < 16; ++r) { p[r] = __expf(S[r] - mnew); psum += p[r]; }
        psum += __shfl_xor(psum, 32);
        l_run = f * l_run + psum;
        #pragma unroll
        for (int r = 0; r < 16; ++r) acc[r] *= f;
        m_run = mnew;

        float other[16];
        #pragma unroll
        for (int r = 0; r < 16; ++r) other[r] = __shfl_xor(p[r], 32);
        half8 pf0, pf1;
        #pragma unroll
        for (int t = 0; t < 4; ++t) {
            pf0[t]     = (_Float16)(hl ? other[4 + t]  : p[t]);
            pf0[4 + t] = (_Float16)(hl ? p[4 + t]      : other[t]);
            pf1[t]     = (_Float16)(hl ? other[12 + t] : p[8 + t]);
            pf1[4 + t] = (_Float16)(hl ? p[12 + t]     : other[8 + t]);
        }

        acc = __builtin_amdgcn_mfma_f32_32x32x16_f16(vf0, pf0, acc, 0, 0, 0);
        acc = __builtin_amdgcn_mfma_f32_32x32x16_f16(vf1, pf1, acc, 0, 0, 0);
    }

    float inv = 1.f / l_run;
    _Float16* ap = a16 + ((size_t)n * kQ + q0 + l31) * 256 + hd * 32;
    #pragma unroll
    for (int r = 0; r < 16; ++r) {
        int c = (r & 3) + 8 * (r >> 2) + 4 * hl;
        ap[c] = (_Float16)(acc[r] * inv);
    }
}

extern "C" void kernel_launch(void* const* d_in, const int* in_sizes, int n_in,
                              void* d_out, int out_size, void* d_ws, size_t ws_size,
                              hipStream_t stream) {
    (void)in_sizes; (void)n_in; (void)out_size; (void)ws_size;
    const float* x     = (const float*)d_in[0];
    const float* h0    = (const float*)d_in[1];
    const float* c0    = (const float*)d_in[2];
    const float* w_in  = (const float*)d_in[3];
    const float* b_in  = (const float*)d_in[4];
    const float* wq_x  = (const float*)d_in[5];
    const float* wq_h  = (const float*)d_in[6];
    const float* wk_x  = (const float*)d_in[7];
    const float* wk_h  = (const float*)d_in[8];
    const float* wv_x  = (const float*)d_in[9];
    const float* wv_h  = (const float*)d_in[10];
    const float* bv    = (const float*)d_in[11];
    const float* wg_a  = (const float*)d_in[12];
    const float* bg    = (const float*)d_in[13];
    const float* wg_x  = (const float*)d_in[14];
    const float* wg_h  = (const float*)d_in[15];
    const float* w_out = (const float*)d_in[16];
    const float* b_out = (const float*)d_in[17];

    _Float16* wh = (_Float16*)d_ws;
    _Float16* xpad16  = wh + H_XPAD;
    _Float16* hpad16  = wh + H_HPAD;
    _Float16* apack1  = wh + H_APACK1;
    _Float16* apack2  = wh + H_APACK2;
    _Float16* apack3  = wh + H_APACK3;
    _Float16* a16     = wh + H_A16;
    _Float16* h16     = wh + H_H16;
    _Float16* q16c    = wh + H_Q16C;
    _Float16* kT16    = wh + H_KT16;
    _Float16* vC16    = wh + H_VC16;
    float* gbuf = (float*)((char*)d_ws + HALF_BYTES) + F_G;

    // fused staging: pack1 + pack_flat x2 + pad + conv1x1 + border-zero
    // (replaces 5 kernels + the 11 MB memset with ONE dispatch)
    staging_kernel<<<4544, 256, 0, stream>>>(
        wq_x, wq_h, wk_x, wk_h, wv_x, wv_h, wg_x, wg_h, wg_a, w_out,
        h0, x, w_in, b_in, apack1, apack2, apack3, xpad16, hpad16);

    // fused q/k/v/gates3x3 GEMM: M=1792, K=4608, N=576 x 16 batches (n-pairs)
    gemm_kernel<0, 0><<<dim3(9, 8, 7), 256, 0, stream>>>(
        apack1, xpad16, hpad16, q16c, kT16, vC16, gbuf, bv, nullptr, nullptr, kKT1, 0);

    // MFMA flash attention -> a16 [n][px][256]
    attn_kernel<<<dim3(9, 128), 128, 0, stream>>>(q16c, kT16, vC16, a16);

    // gates = wg_a . a + bg + gbuf, fused LSTM -> h16 [n][px][256]
    gemm_kernel<1, 3><<<dim3(9, 8, 4), 256, 0, stream>>>(
        apack2, a16, nullptr, nullptr, nullptr, nullptr, gbuf, bg, c0, h16, kKT2, 256);

    // out = w_out . h + b_out : M=256 -> 1 m-tile
    gemm_kernel<1, 2><<<dim3(9, 8, 1), 256, 0, stream>>>(
        apack3, h16, nullptr, nullptr, nullptr, nullptr, (float*)d_out, b_out, nullptr, nullptr, kKT3, 256);
}

// Round 10
// 388.779 us; speedup vs baseline: 1.0484x; 1.0030x over previous
//
#include <hip/hip_runtime.h>
#include <cstddef>

// ---- problem constants ----
constexpr int kN  = 16;
constexpr int kI  = 128;
constexpr int kHW = 24;
constexpr int kQ  = 576;    // 24*24
constexpr int kD  = 484;    // 22*22
constexpr int kDP = 512;    // padded d
constexpr int kPP = 676;    // 26*26 padded

// GEMM K-tiling (BK=64)
constexpr int kKT1 = 72;    // K1 = 4608 / 64
constexpr int kKT2 = 4;     // K2 = 256 / 64
constexpr int kKT3 = 4;     // K3 = 256 / 64

// ---- workspace layout ----
// half region (element offsets into _Float16*)
constexpr size_t H_XPAD   = 0;                          // [16][26][26][256] NHWC
constexpr size_t H_HPAD   = 2768896;                    // [16][26][26][256] NHWC
constexpr size_t H_APACK1 = 5537792;                    // 1792*4608 frag-tiled (256-row, BK64)
constexpr size_t H_APACK2 = 13795328;                   // 1024*256 frag-tiled
constexpr size_t H_APACK3 = 14057472;                   // 256*256 frag-tiled
constexpr size_t H_A16    = 14123008;                   // [16][576][256]
constexpr size_t H_H16    = 16482304;                   // [16][576][256]
constexpr size_t H_Q16C   = 18841600;                   // [16][256][576]  (c-major)
constexpr size_t H_KT16   = 21200896;                   // [128 head][4 chi][512 d][8 clo]
constexpr size_t H_VC16   = 23298048;                   // [128 head][64 dhi][32 c][8 dlo]
constexpr size_t HALF_ELEMS = 25395200;
constexpr size_t HALF_BYTES = HALF_ELEMS * 2;           // 50,790,400
// float region at d_ws + HALF_BYTES
constexpr size_t F_G = 0;                               // [16][1024][576]

constexpr size_t kXHGap = H_HPAD - H_XPAD;              // hpad - xpad element gap

using half8    = __attribute__((ext_vector_type(8))) _Float16;
using floatx16 = __attribute__((ext_vector_type(16))) float;

__device__ __forceinline__ float sigm(float x) { return 1.0f / (1.0f + __expf(-x)); }
__device__ __forceinline__ float tanh_f(float x) {
    float e = __expf(2.0f * fabsf(x));
    float r = 1.0f - 2.0f / (e + 1.0f);
    return copysignf(r, x);
}

// 16B-aligned vector load/store (emits b128 ops)
__device__ __forceinline__ half8 LD8(const _Float16* p) { return *(const half8*)p; }
__device__ __forceinline__ void ST8(_Float16* p, half8 v) { *(half8*)p = v; }

// ---------------- fused staging kernel (frozen from R9) ----------------
// Block roles:
//   [0,896)      pack1: coalesced LDS-transpose of 3x3 weights -> apack1
//   [896,1024)   pack_flat PERM=1: wg_a -> apack2 (gate-interleaved rows)
//   [1024,1056)  pack_flat PERM=0: w_out -> apack3
//   [1056,2208)  pad_nhwc: h0 fp32 NCHW -> hpad16 NHWC interior (1152 blocks)
//   [2208,4512)  conv1x1: xin = w_in.x + b_in -> xpad16 interior (2304 blocks)
//   [4512,4544)  border zero: 100-px frame of each (img, n) image
__global__ __launch_bounds__(256)
void staging_kernel(const float* __restrict__ wq_x, const float* __restrict__ wq_h,
                    const float* __restrict__ wk_x, const float* __restrict__ wk_h,
                    const float* __restrict__ wv_x, const float* __restrict__ wv_h,
                    const float* __restrict__ wg_x, const float* __restrict__ wg_h,
                    const float* __restrict__ wg_a, const float* __restrict__ w_out,
                    const float* __restrict__ h0, const float* __restrict__ x,
                    const float* __restrict__ w_in, const float* __restrict__ b_in,
                    _Float16* __restrict__ apack1, _Float16* __restrict__ apack2,
                    _Float16* __restrict__ apack3, _Float16* __restrict__ xpad16,
                    _Float16* __restrict__ hpad16) {
    __shared__ float ls[9216];                 // 36 KB union (pack1 / pad tile)
    const int b = blockIdx.x;
    const int tid = threadIdx.x;

    if (b < 896) {
        const int rg   = b & 15;
        const int icb  = (b >> 4) & 3;
        const int srcs = (b >> 6) & 1;
        const int mt   = b >> 7;
        const float *s1, *s2;
        if (mt == 0)      { s1 = wq_x; s2 = wq_h; }
        else if (mt == 1) { s1 = wk_x; s2 = wk_h; }
        else if (mt == 2) { s1 = wv_x; s2 = wv_h; }
        else              { s1 = wg_x; s2 = wg_h; }
        const float* sp = srcs ? s2 : s1;
        #pragma unroll
        for (int rep = 0; rep < 36; ++rep) {
            int f = rep * 256 + tid;
            int row = f / 576, off = f - row * 576;
            int mm;
            if (mt < 3) {
                mm = rg * 16 + row;
            } else {
                int mp = (mt - 3) * 256 + rg * 16 + row;     // m - 768
                mm = (mp & 3) * 256 + (mp >> 2);             // gate interleave
            }
            ls[f] = sp[(size_t)mm * 2304 + (size_t)icb * 576 + off];
        }
        __syncthreads();
        const size_t mt_base = (size_t)mt * 72 * 16384;
        for (int c = tid; c < 1152; c += 256) {
            int row = c / 72, rem = c - row * 72;
            int tap = rem >> 3, khl = rem & 7;
            int kk = khl >> 1, hl = khl & 1;
            int kt = srcs * 36 + tap * 4 + icb;
            const float* lp = ls + row * 576 + (kk * 16 + hl * 8) * 9 + tap;
            half8 v;
            #pragma unroll
            for (int j = 0; j < 8; ++j) v[j] = (_Float16)lp[j * 9];
            ST8(apack1 + mt_base + (size_t)kt * 16384 + kk * 4096 + hl * 2048
                    + (size_t)(rg * 16 + row) * 8, v);
        }
    } else if (b < 1056) {
        const int perm = (b < 1024) ? 1 : 0;
        const float* src = perm ? wg_a : w_out;
        _Float16* dst = perm ? apack2 : apack3;
        int p8 = (b - (perm ? 896 : 1024)) * 256 + tid;
        int row = p8 & 255, hl = (p8 >> 8) & 1, kk = (p8 >> 9) & 3;
        int tile = p8 >> 11;
        int mt = tile >> 2, kt = tile & 3;                 // Ktiles = 4
        int m = mt * 256 + row;
        int k0 = kt * 64 + kk * 16 + hl * 8;
        int mm = perm ? ((m & 3) * 256 + (m >> 2)) : m;
        const float* sp = src + (size_t)mm * 256 + k0;
        half8 v;
        #pragma unroll
        for (int j = 0; j < 8; ++j) v[j] = (_Float16)sp[j];
        ST8(dst + (size_t)p8 * 8, v);
    } else if (b < 2208) {
        float (*tile)[65] = (float(*)[65])ls;              // 32x65 floats
        const int bb = b - 1056;
        const int pxt = bb % 9, ict = (bb / 9) & 7, n = bb / 72;
        {
            int icl = tid >> 6, pxl = tid & 63;
            #pragma unroll
            for (int rep = 0; rep < 8; ++rep) {
                int ic = ict * 32 + rep * 4 + icl;
                tile[rep * 4 + icl][pxl] = h0[((size_t)n * 256 + ic) * kQ + pxt * 64 + pxl];
            }
        }
        __syncthreads();
        {
            int icl = tid & 31, pxl0 = tid >> 5;
            #pragma unroll
            for (int rep = 0; rep < 8; ++rep) {
                int pxl = rep * 8 + pxl0;
                int px = pxt * 64 + pxl;
                int y = px / kHW, xx = px - y * kHW;
                hpad16[((size_t)n * kPP + (size_t)(y + 1) * 26 + (xx + 1)) * 256 + ict * 32 + icl] =
                    (_Float16)tile[icl][pxl];
            }
        }
    } else if (b < 4512) {
        const int bb = b - 2208;
        const int bx = bb % 9, by = (bb / 9) & 15, n = bb / 144;
        const int tx = tid & 63, ty = tid >> 6;
        int px = bx * 64 + tx;
        int oc0 = __builtin_amdgcn_readfirstlane(by * 16 + ty * 4);
        const float* ip = x + (size_t)n * kI * kQ + px;
        float acc[4] = {0.f, 0.f, 0.f, 0.f};
        #pragma unroll 4
        for (int ic = 0; ic < kI; ++ic) {
            float xv = ip[(size_t)ic * kQ];
            #pragma unroll
            for (int j = 0; j < 4; ++j) acc[j] = fmaf(xv, w_in[(size_t)(oc0 + j) * kI + ic], acc[j]);
        }
        int y = px / kHW, xc = px - y * kHW;
        _Float16* op = xpad16 + ((size_t)n * kPP + (size_t)(y + 1) * 26 + (xc + 1)) * 256 + oc0;
        #pragma unroll
        for (int j = 0; j < 4; ++j) op[j] = (_Float16)(acc[j] + b_in[oc0 + j]);
    } else {
        const int bb = b - 4512;
        _Float16* img = (bb >> 4) ? hpad16 : xpad16;
        const int n = bb & 15;
        _Float16* base = img + (size_t)n * kPP * 256;
        #pragma unroll 4
        for (int rep = 0; rep < 100; ++rep) {
            int y, xx;
            if (rep < 26)      { y = 0;        xx = rep; }
            else if (rep < 52) { y = 25;       xx = rep - 26; }
            else if (rep < 76) { y = rep - 51; xx = 0; }       // y = 1..24
            else               { y = rep - 75; xx = 25; }      // y = 1..24
            base[((size_t)y * 26 + xx) * 256 + tid] = (_Float16)0.f;
        }
    }
}

// ---------------- fused MFMA GEMM (BK=64, templated batch-pairing) ----------------
// NPAIR=2 (gemm1): TWO n-batches per block, one A read (R7 VMEM-byte fix).
// NPAIR=1 (gemm2/3): single n, small accs -> (256,3) bounds, 2x grid for the
// occupancy-starved tail kernels (gemm3 was 72 blocks = 28% CU busy).
// K/V epilogue layouts (R10): coalesced-for-attn
//   kT16: [head][chi4][d512][clo8]   idx = ((head*4+((c>>3)&3))*512 + d)*8 + (c&7)
//   vC16: [head][dhi64][c32][dlo8]   idx = ((head*64+(d>>3))*32 + c)*8 + (d&7)
template<int BMODE, int EMODE, int NPAIR>
__global__ __launch_bounds__(256, NPAIR == 2 ? 2 : 3)
void gemm_kernel(const _Float16* __restrict__ Apack,
                 const _Float16* __restrict__ B1, const _Float16* __restrict__ B2,
                 _Float16* __restrict__ q16, _Float16* __restrict__ k16,
                 _Float16* __restrict__ v16, float* __restrict__ pf,
                 const float* __restrict__ bias, const float* __restrict__ c0p,
                 _Float16* __restrict__ h16o, int Ktiles, int Ktot) {
    __shared__ _Float16 Bs[2][NPAIR][4096];    // [dbuf][nidx][64px*64k]
    const int tid = threadIdx.x;
    const int wv = tid >> 6, lane = tid & 63, l31 = lane & 31, hl = lane >> 5;
    const int nt = blockIdx.x, np = blockIdx.y, mt = blockIdx.z;
    const int n0 = np * NPAIR;

    floatx16 c0_00 = {}, c0_01 = {}, c0_10 = {}, c0_11 = {};   // n0: mi,ci
    floatx16 c1_00 = {}, c1_01 = {}, c1_10 = {}, c1_11 = {};   // n1 (NPAIR==2)

    const _Float16* abase = Apack + (size_t)mt * Ktiles * 16384;
    const int aoff = hl * 2048 + (wv * 64 + l31) * 8;

    const int px_l = tid >> 2, bc = tid & 3;
    const int px = nt * 64 + px_l;
    const int by = px / kHW, bx = px - by * kHW;

    const int sw = px_l & 7;
    const int wofs0 = px_l * 64 + (((2 * bc) ^ sw) << 3);
    const int wofs1 = px_l * 64 + (((2 * bc + 1) ^ sw) << 3);
    const int rsw = l31 & 7;
    const int ro0 = l31 * 64 + (((0 + hl) ^ rsw) << 3);    // kkc0; +2048 for ci=1
    const int ro1 = l31 * 64 + (((2 + hl) ^ rsw) << 3);
    const int ro2 = l31 * 64 + (((4 + hl) ^ rsw) << 3);
    const int ro3 = l31 * 64 + (((6 + hl) ^ rsw) << 3);

    const _Float16 *bsx0 = nullptr, *bsx1 = nullptr;
    if (BMODE == 0) {
        bsx0 = B1 + ((size_t)n0 * kPP + (size_t)by * 26 + bx) * 256 + (size_t)bc * 16;
        if (NPAIR == 2) bsx1 = bsx0 + (size_t)kPP * 256;
    } else {
        bsx0 = B1 + ((size_t)n0 * kQ + px) * Ktot + bc * 16;
        if (NPAIR == 2) bsx1 = bsx0 + (size_t)kQ * Ktot;
    }

    auto loadB = [&](const _Float16* base, int kt, half8& lo, half8& hi) {
        if (BMODE == 0) {
            int srcs = (kt >= 36) ? 1 : 0;
            int ktl = kt - srcs * 36;
            int tap = ktl >> 2, icb = (ktl & 3) << 6;
            int ty = (tap * 11) >> 5;          // tap/3 for 0..9
            int tx = tap - ty * 3;
            const _Float16* p = base + (size_t)srcs * kXHGap
                              + ((size_t)(ty * 26 + tx)) * 256 + icb;
            lo = LD8(p); hi = LD8(p + 8);
        } else {
            const _Float16* p = base + kt * 64;
            lo = LD8(p); hi = LD8(p + 8);
        }
    };

    half8 e0l, e0h, e1l, e1h, o0l, o0h, o1l, o1h;
    loadB(bsx0, 0, e0l, e0h);
    if (NPAIR == 2) loadB(bsx1, 0, e1l, e1h);
    loadB(bsx0, 1, o0l, o0h);
    if (NPAIR == 2) loadB(bsx1, 1, o1l, o1h);

    for (int kt = 0; kt < Ktiles; kt += 2) {
        const _Float16* ab = abase + (size_t)kt * 16384;
        // ================= even step: buffer 0 = tile kt =================
        ST8(&Bs[0][0][wofs0], e0l); ST8(&Bs[0][0][wofs1], e0h);
        if (NPAIR == 2) { ST8(&Bs[0][NPAIR - 1][wofs0], e1l); ST8(&Bs[0][NPAIR - 1][wofs1], e1h); }
        half8 aA = LD8(ab + aoff),          aB = LD8(ab + aoff + 256);          // kkc0
        half8 aC = LD8(ab + 4096 + aoff),   aD = LD8(ab + 4096 + aoff + 256);   // kkc1
        half8 f0 = LD8(ab + 8192 + aoff),   f1 = LD8(ab + 8192 + aoff + 256);   // kkc2
        half8 f2 = LD8(ab + 12288 + aoff),  f3 = LD8(ab + 12288 + aoff + 256);  // kkc3
        loadB(bsx0, kt + 2, e0l, e0h);
        if (NPAIR == 2) loadB(bsx1, kt + 2, e1l, e1h);                          // 2-deep B
        asm volatile("s_waitcnt lgkmcnt(0)" ::: "memory");
        __builtin_amdgcn_s_barrier();
        {
            const _Float16* bb0 = Bs[0][0];
            half8 b00 = LD8(bb0 + ro0), b01 = LD8(bb0 + ro0 + 2048);
            half8 b10 = LD8(bb0 + ro1), b11 = LD8(bb0 + ro1 + 2048);
            __builtin_amdgcn_s_setprio(1);
            c0_00 = __builtin_amdgcn_mfma_f32_32x32x16_f16(aA, b00, c0_00, 0, 0, 0);
            c0_01 = __builtin_amdgcn_mfma_f32_32x32x16_f16(aA, b01, c0_01, 0, 0, 0);
            c0_10 = __builtin_amdgcn_mfma_f32_32x32x16_f16(aB, b00, c0_10, 0, 0, 0);
            c0_11 = __builtin_amdgcn_mfma_f32_32x32x16_f16(aB, b01, c0_11, 0, 0, 0);
            c0_00 = __builtin_amdgcn_mfma_f32_32x32x16_f16(aC, b10, c0_00, 0, 0, 0);
            c0_01 = __builtin_amdgcn_mfma_f32_32x32x16_f16(aC, b11, c0_01, 0, 0, 0);
            c0_10 = __builtin_amdgcn_mfma_f32_32x32x16_f16(aD, b10, c0_10, 0, 0, 0);
            c0_11 = __builtin_amdgcn_mfma_f32_32x32x16_f16(aD, b11, c0_11, 0, 0, 0);
            __builtin_amdgcn_s_setprio(0);
            b00 = LD8(bb0 + ro2); b01 = LD8(bb0 + ro2 + 2048);
            b10 = LD8(bb0 + ro3); b11 = LD8(bb0 + ro3 + 2048);
            __builtin_amdgcn_s_setprio(1);
            c0_00 = __builtin_amdgcn_mfma_f32_32x32x16_f16(f0, b00, c0_00, 0, 0, 0);
            c0_01 = __builtin_amdgcn_mfma_f32_32x32x16_f16(f0, b01, c0_01, 0, 0, 0);
            c0_10 = __builtin_amdgcn_mfma_f32_32x32x16_f16(f1, b00, c0_10, 0, 0, 0);
            c0_11 = __builtin_amdgcn_mfma_f32_32x32x16_f16(f1, b01, c0_11, 0, 0, 0);
            c0_00 = __builtin_amdgcn_mfma_f32_32x32x16_f16(f2, b10, c0_00, 0, 0, 0);
            c0_01 = __builtin_amdgcn_mfma_f32_32x32x16_f16(f2, b11, c0_01, 0, 0, 0);
            c0_10 = __builtin_amdgcn_mfma_f32_32x32x16_f16(f3, b10, c0_10, 0, 0, 0);
            c0_11 = __builtin_amdgcn_mfma_f32_32x32x16_f16(f3, b11, c0_11, 0, 0, 0);
            __builtin_amdgcn_s_setprio(0);
            if (NPAIR == 2) {
                const _Float16* bb1 = Bs[0][NPAIR - 1];
                b00 = LD8(bb1 + ro0); b01 = LD8(bb1 + ro0 + 2048);
                b10 = LD8(bb1 + ro1); b11 = LD8(bb1 + ro1 + 2048);
                __builtin_amdgcn_s_setprio(1);
                c1_00 = __builtin_amdgcn_mfma_f32_32x32x16_f16(aA, b00, c1_00, 0, 0, 0);
                c1_01 = __builtin_amdgcn_mfma_f32_32x32x16_f16(aA, b01, c1_01, 0, 0, 0);
                c1_10 = __builtin_amdgcn_mfma_f32_32x32x16_f16(aB, b00, c1_10, 0, 0, 0);
                c1_11 = __builtin_amdgcn_mfma_f32_32x32x16_f16(aB, b01, c1_11, 0, 0, 0);
                c1_00 = __builtin_amdgcn_mfma_f32_32x32x16_f16(aC, b10, c1_00, 0, 0, 0);
                c1_01 = __builtin_amdgcn_mfma_f32_32x32x16_f16(aC, b11, c1_01, 0, 0, 0);
                c1_10 = __builtin_amdgcn_mfma_f32_32x32x16_f16(aD, b10, c1_10, 0, 0, 0);
                c1_11 = __builtin_amdgcn_mfma_f32_32x32x16_f16(aD, b11, c1_11, 0, 0, 0);
                __builtin_amdgcn_s_setprio(0);
                b00 = LD8(bb1 + ro2); b01 = LD8(bb1 + ro2 + 2048);
                b10 = LD8(bb1 + ro3); b11 = LD8(bb1 + ro3 + 2048);
                __builtin_amdgcn_s_setprio(1);
                c1_00 = __builtin_amdgcn_mfma_f32_32x32x16_f16(f0, b00, c1_00, 0, 0, 0);
                c1_01 = __builtin_amdgcn_mfma_f32_32x32x16_f16(f0, b01, c1_01, 0, 0, 0);
                c1_10 = __builtin_amdgcn_mfma_f32_32x32x16_f16(f1, b00, c1_10, 0, 0, 0);
                c1_11 = __builtin_amdgcn_mfma_f32_32x32x16_f16(f1, b01, c1_11, 0, 0, 0);
                c1_00 = __builtin_amdgcn_mfma_f32_32x32x16_f16(f2, b10, c1_00, 0, 0, 0);
                c1_01 = __builtin_amdgcn_mfma_f32_32x32x16_f16(f2, b11, c1_01, 0, 0, 0);
                c1_10 = __builtin_amdgcn_mfma_f32_32x32x16_f16(f3, b10, c1_10, 0, 0, 0);
                c1_11 = __builtin_amdgcn_mfma_f32_32x32x16_f16(f3, b11, c1_11, 0, 0, 0);
                __builtin_amdgcn_s_setprio(0);
            }
        }
        // ================= odd step: buffer 1 = tile kt+1 =================
        const _Float16* ab2 = ab + 16384;
        ST8(&Bs[1][0][wofs0], o0l); ST8(&Bs[1][0][wofs1], o0h);
        if (NPAIR == 2) { ST8(&Bs[1][NPAIR - 1][wofs0], o1l); ST8(&Bs[1][NPAIR - 1][wofs1], o1h); }
        half8 gA = LD8(ab2 + aoff),          gB = LD8(ab2 + aoff + 256);
        half8 gC = LD8(ab2 + 4096 + aoff),   gD = LD8(ab2 + 4096 + aoff + 256);
        half8 g0 = LD8(ab2 + 8192 + aoff),   g1 = LD8(ab2 + 8192 + aoff + 256);
        half8 g2 = LD8(ab2 + 12288 + aoff),  g3 = LD8(ab2 + 12288 + aoff + 256);
        loadB(bsx0, kt + 3, o0l, o0h);
        if (NPAIR == 2) loadB(bsx1, kt + 3, o1l, o1h);
        asm volatile("s_waitcnt lgkmcnt(0)" ::: "memory");
        __builtin_amdgcn_s_barrier();
        {
            const _Float16* bb0 = Bs[1][0];
            half8 b00 = LD8(bb0 + ro0), b01 = LD8(bb0 + ro0 + 2048);
            half8 b10 = LD8(bb0 + ro1), b11 = LD8(bb0 + ro1 + 2048);
            __builtin_amdgcn_s_setprio(1);
            c0_00 = __builtin_amdgcn_mfma_f32_32x32x16_f16(gA, b00, c0_00, 0, 0, 0);
            c0_01 = __builtin_amdgcn_mfma_f32_32x32x16_f16(gA, b01, c0_01, 0, 0, 0);
            c0_10 = __builtin_amdgcn_mfma_f32_32x32x16_f16(gB, b00, c0_10, 0, 0, 0);
            c0_11 = __builtin_amdgcn_mfma_f32_32x32x16_f16(gB, b01, c0_11, 0, 0, 0);
            c0_00 = __builtin_amdgcn_mfma_f32_32x32x16_f16(gC, b10, c0_00, 0, 0, 0);
            c0_01 = __builtin_amdgcn_mfma_f32_32x32x16_f16(gC, b11, c0_01, 0, 0, 0);
            c0_10 = __builtin_amdgcn_mfma_f32_32x32x16_f16(gD, b10, c0_10, 0, 0, 0);
            c0_11 = __builtin_amdgcn_mfma_f32_32x32x16_f16(gD, b11, c0_11, 0, 0, 0);
            __builtin_amdgcn_s_setprio(0);
            b00 = LD8(bb0 + ro2); b01 = LD8(bb0 + ro2 + 2048);
            b10 = LD8(bb0 + ro3); b11 = LD8(bb0 + ro3 + 2048);
            __builtin_amdgcn_s_setprio(1);
            c0_00 = __builtin_amdgcn_mfma_f32_32x32x16_f16(g0, b00, c0_00, 0, 0, 0);
            c0_01 = __builtin_amdgcn_mfma_f32_32x32x16_f16(g0, b01, c0_01, 0, 0, 0);
            c0_10 = __builtin_amdgcn_mfma_f32_32x32x16_f16(g1, b00, c0_10, 0, 0, 0);
            c0_11 = __builtin_amdgcn_mfma_f32_32x32x16_f16(g1, b01, c0_11, 0, 0, 0);
            c0_00 = __builtin_amdgcn_mfma_f32_32x32x16_f16(g2, b10, c0_00, 0, 0, 0);
            c0_01 = __builtin_amdgcn_mfma_f32_32x32x16_f16(g2, b11, c0_01, 0, 0, 0);
            c0_10 = __builtin_amdgcn_mfma_f32_32x32x16_f16(g3, b10, c0_10, 0, 0, 0);
            c0_11 = __builtin_amdgcn_mfma_f32_32x32x16_f16(g3, b11, c0_11, 0, 0, 0);
            __builtin_amdgcn_s_setprio(0);
            if (NPAIR == 2) {
                const _Float16* bb1 = Bs[1][NPAIR - 1];
                b00 = LD8(bb1 + ro0); b01 = LD8(bb1 + ro0 + 2048);
                b10 = LD8(bb1 + ro1); b11 = LD8(bb1 + ro1 + 2048);
                __builtin_amdgcn_s_setprio(1);
                c1_00 = __builtin_amdgcn_mfma_f32_32x32x16_f16(gA, b00, c1_00, 0, 0, 0);
                c1_01 = __builtin_amdgcn_mfma_f32_32x32x16_f16(gA, b01, c1_01, 0, 0, 0);
                c1_10 = __builtin_amdgcn_mfma_f32_32x32x16_f16(gB, b00, c1_10, 0, 0, 0);
                c1_11 = __builtin_amdgcn_mfma_f32_32x32x16_f16(gB, b01, c1_11, 0, 0, 0);
                c1_00 = __builtin_amdgcn_mfma_f32_32x32x16_f16(gC, b10, c1_00, 0, 0, 0);
                c1_01 = __builtin_amdgcn_mfma_f32_32x32x16_f16(gC, b11, c1_01, 0, 0, 0);
                c1_10 = __builtin_amdgcn_mfma_f32_32x32x16_f16(gD, b10, c1_10, 0, 0, 0);
                c1_11 = __builtin_amdgcn_mfma_f32_32x32x16_f16(gD, b11, c1_11, 0, 0, 0);
                __builtin_amdgcn_s_setprio(0);
                b00 = LD8(bb1 + ro2); b01 = LD8(bb1 + ro2 + 2048);
                b10 = LD8(bb1 + ro3); b11 = LD8(bb1 + ro3 + 2048);
                __builtin_amdgcn_s_setprio(1);
                c1_00 = __builtin_amdgcn_mfma_f32_32x32x16_f16(g0, b00, c1_00, 0, 0, 0);
                c1_01 = __builtin_amdgcn_mfma_f32_32x32x16_f16(g0, b01, c1_01, 0, 0, 0);
                c1_10 = __builtin_amdgcn_mfma_f32_32x32x16_f16(g1, b00, c1_10, 0, 0, 0);
                c1_11 = __builtin_amdgcn_mfma_f32_32x32x16_f16(g1, b01, c1_11, 0, 0, 0);
                c1_00 = __builtin_amdgcn_mfma_f32_32x32x16_f16(g2, b10, c1_00, 0, 0, 0);
                c1_01 = __builtin_amdgcn_mfma_f32_32x32x16_f16(g2, b11, c1_01, 0, 0, 0);
                c1_10 = __builtin_amdgcn_mfma_f32_32x32x16_f16(g3, b10, c1_10, 0, 0, 0);
                c1_11 = __builtin_amdgcn_mfma_f32_32x32x16_f16(g3, b11, c1_11, 0, 0, 0);
                __builtin_amdgcn_s_setprio(0);
            }
        }
    }

    // epilogue per n: C/D layout col=lane&31, row=(reg&3)+8*(reg>>2)+4*(lane>>5)
    auto epi = [&](int n, const floatx16& av00, const floatx16& av01,
                   const floatx16& av10, const floatx16& av11) {
        if (EMODE == 3) {
            const int rrb = mt * 64 + wv * 16;
            #pragma unroll
            for (int mi = 0; mi < 2; ++mi) {
                #pragma unroll
                for (int ci = 0; ci < 2; ++ci) {
                    const floatx16& av = mi ? (ci ? av11 : av10) : (ci ? av01 : av00);
                    const int pxe = nt * 64 + ci * 32 + l31;
                    #pragma unroll
                    for (int tq = 0; tq < 4; ++tq) {
                        int rr = rrb + mi * 8 + 2 * tq + hl;
                        size_t gb = ((size_t)n * 1024 + 4 * rr) * kQ + pxe;
                        float iv = av[4 * tq + 0] + pf[gb]          + bias[rr];
                        float fv = av[4 * tq + 1] + pf[gb + kQ]     + bias[256 + rr];
                        float gv = av[4 * tq + 2] + pf[gb + 2 * kQ] + bias[512 + rr];
                        float ov = av[4 * tq + 3] + pf[gb + 3 * kQ] + bias[768 + rr];
                        float cc = sigm(fv) * c0p[((size_t)n * 256 + rr) * kQ + pxe]
                                 + sigm(iv) * tanh_f(gv);
                        float hh = sigm(ov) * tanh_f(cc);
                        h16o[((size_t)n * kQ + pxe) * 256 + rr] = (_Float16)hh;
                    }
                }
            }
            return;
        }
        const int mb0 = mt * 256 + wv * 64;
        #pragma unroll
        for (int mi = 0; mi < 2; ++mi) {
            #pragma unroll
            for (int ci = 0; ci < 2; ++ci) {
                const floatx16& av = mi ? (ci ? av11 : av10) : (ci ? av01 : av00);
                const int pxe = nt * 64 + ci * 32 + l31;
                #pragma unroll
                for (int r = 0; r < 16; ++r) {
                    int rowi = (r & 3) + 8 * (r >> 2) + 4 * hl;
                    int m = mb0 + mi * 32 + rowi;
                    float val = av[r];
                    if (EMODE == 0) {
                        if (m < 256) {
                            q16[((size_t)n * 256 + m) * kQ + pxe] = (_Float16)val;
                        } else if (m < 768) {
                            int ch = m & 255;
                            int yy = pxe / kHW, xx = pxe - yy * kHW;
                            if (yy >= 1 && yy <= 22 && xx >= 1 && xx <= 22) {
                                int d = (yy - 1) * 22 + (xx - 1);
                                int head = n * 8 + (ch >> 5);
                                if (m < 512) {
                                    // kT16 [head][chi4][d512][clo8]
                                    k16[(((size_t)head * 4 + ((ch >> 3) & 3)) * kDP + d) * 8 + (ch & 7)] = (_Float16)val;
                                } else {
                                    // vC16 [head][dhi64][c32][dlo8]
                                    v16[(((size_t)head * 64 + (d >> 3)) * 32 + (ch & 31)) * 8 + (d & 7)] = (_Float16)(val + bias[ch]);
                                }
                            }
                        } else {
                            pf[((size_t)n * 1024 + (m - 768)) * kQ + pxe] = val;
                        }
                    } else {
                        pf[((size_t)n * 256 + m) * kQ + pxe] = val + bias[m];
                    }
                }
            }
        }
    };
    epi(n0, c0_00, c0_01, c0_10, c0_11);
    if (NPAIR == 2) epi(n0 + 1, c1_00, c1_01, c1_10, c1_11);
}

// ---------------- MFMA flash attention (coalesced K/V layouts) ----------------
// kT16 [head][chi4][d512][clo8]: kf load lane-addr = ((head*4+chi)*512 + d0+l31)*8+j
//   -> per-lane 16B contiguous in l31: fully coalesced b128.
// vC16 [head][dhi64][c32][dlo8]: vf load lane-addr = ((head*64+d0/8+hl)*32+l31)*8+j
//   -> fully coalesced b128. (Was lane-stride 64B / 1KB = 32-64 lines per instr.)
__global__ __launch_bounds__(128)
void attn_kernel(const _Float16* __restrict__ q16c, const _Float16* __restrict__ kT16,
                 const _Float16* __restrict__ vC16, _Float16* __restrict__ a16) {
    const int lane = threadIdx.x & 63;
    const int wv   = threadIdx.x >> 6;
    const int l31 = lane & 31, hl = lane >> 5;
    const int lid = blockIdx.x + 9 * blockIdx.y;
    const int swz = (lid & 7) * 144 + (lid >> 3);
    const int bx = swz % 9, head = swz / 9;     // head = n*8 + hd
    const int n = head >> 3, hd = head & 7;
    const int qt = bx * 2 + wv;                 // 0..17
    const int q0 = qt * 32;

    half8 qf0, qf1;
    {
        const _Float16* qb = q16c + ((size_t)n * 256 + hd * 32 + hl * 8) * kQ + q0 + l31;
        #pragma unroll
        for (int j = 0; j < 8; ++j) {
            qf0[j] = qb[(size_t)j * kQ];
            qf1[j] = qb[(size_t)(16 + j) * kQ];
        }
    }

    // coalesced bases (see layout comments above)
    const _Float16* kb0 = kT16 + ((size_t)(head * 4 + hl) * kDP + l31) * 8;         // chi=hl
    const _Float16* kb1 = kT16 + ((size_t)(head * 4 + 2 + hl) * kDP + l31) * 8;     // chi=2+hl
    const _Float16* vb  = vC16 + (size_t)head * 16384 + (size_t)hl * 256 + (size_t)l31 * 8;

    floatx16 acc = {};
    float m_run = -1e30f, l_run = 0.f;

    half8 kf0 = LD8(kb0);
    half8 kf1 = LD8(kb1);

    for (int dt = 0; dt < 16; ++dt) {
        const int d0 = dt * 32;
        floatx16 S = {};
        S = __builtin_amdgcn_mfma_f32_32x32x16_f16(kf0, qf0, S, 0, 0, 0);
        S = __builtin_amdgcn_mfma_f32_32x32x16_f16(kf1, qf1, S, 0, 0, 0);

        half8 vf0 = LD8(vb + (size_t)d0 * 32);          // dhi = d0/8 + hl
        half8 vf1 = LD8(vb + (size_t)d0 * 32 + 512);    // +2 dhi
        if (dt < 15) {
            kf0 = LD8(kb0 + (size_t)(d0 + 32) * 8);
            kf1 = LD8(kb1 + (size_t)(d0 + 32) * 8);
        }

        if (dt == 15) {
            #pragma unroll
            for (int r = 0; r < 16; ++r)
                if (!(hl == 0 && r < 4)) S[r] = -1e30f;
        }

        float tmax = S[0];
        #pragma unroll
        for (int r = 1; r < 16; ++r) tmax = fmaxf(tmax, S[r]);
        tmax = fmaxf(tmax, __shfl_xor(tmax, 32));
        float mnew = fmaxf(m_run, tmax);
        float f = __expf(m_run - mnew);
        float p[16], psum = 0.f;
        #pragma unroll
        for (int r = 0; r < 16; ++r) { p[r] = __expf(S[r] - mnew); psum += p[r]; }
        psum += __shfl_xor(psum, 32);
        l_run = f * l_run + psum;
        #pragma unroll
        for (int r = 0; r < 16; ++r) acc[r] *= f;
        m_run = mnew;

        float other[16];
        #pragma unroll
        for (int r = 0; r < 16; ++r) other[r] = __shfl_xor(p[r], 32);
        half8 pf0, pf1;
        #pragma unroll
        for (int t = 0; t < 4; ++t) {
            pf0[t]     = (_Float16)(hl ? other[4 + t]  : p[t]);
            pf0[4 + t] = (_Float16)(hl ? p[4 + t]      : other[t]);
            pf1[t]     = (_Float16)(hl ? other[12 + t] : p[8 + t]);
            pf1[4 + t] = (_Float16)(hl ? p[12 + t]     : other[8 + t]);
        }

        acc = __builtin_amdgcn_mfma_f32_32x32x16_f16(vf0, pf0, acc, 0, 0, 0);
        acc = __builtin_amdgcn_mfma_f32_32x32x16_f16(vf1, pf1, acc, 0, 0, 0);
    }

    float inv = 1.f / l_run;
    _Float16* ap = a16 + ((size_t)n * kQ + q0 + l31) * 256 + hd * 32;
    #pragma unroll
    for (int r = 0; r < 16; ++r) {
        int c = (r & 3) + 8 * (r >> 2) + 4 * hl;
        ap[c] = (_Float16)(acc[r] * inv);
    }
}

extern "C" void kernel_launch(void* const* d_in, const int* in_sizes, int n_in,
                              void* d_out, int out_size, void* d_ws, size_t ws_size,
                              hipStream_t stream) {
    (void)in_sizes; (void)n_in; (void)out_size; (void)ws_size;
    const float* x     = (const float*)d_in[0];
    const float* h0    = (const float*)d_in[1];
    const float* c0    = (const float*)d_in[2];
    const float* w_in  = (const float*)d_in[3];
    const float* b_in  = (const float*)d_in[4];
    const float* wq_x  = (const float*)d_in[5];
    const float* wq_h  = (const float*)d_in[6];
    const float* wk_x  = (const float*)d_in[7];
    const float* wk_h  = (const float*)d_in[8];
    const float* wv_x  = (const float*)d_in[9];
    const float* wv_h  = (const float*)d_in[10];
    const float* bv    = (const float*)d_in[11];
    const float* wg_a  = (const float*)d_in[12];
    const float* bg    = (const float*)d_in[13];
    const float* wg_x  = (const float*)d_in[14];
    const float* wg_h  = (const float*)d_in[15];
    const float* w_out = (const float*)d_in[16];
    const float* b_out = (const float*)d_in[17];

    _Float16* wh = (_Float16*)d_ws;
    _Float16* xpad16  = wh + H_XPAD;
    _Float16* hpad16  = wh + H_HPAD;
    _Float16* apack1  = wh + H_APACK1;
    _Float16* apack2  = wh + H_APACK2;
    _Float16* apack3  = wh + H_APACK3;
    _Float16* a16     = wh + H_A16;
    _Float16* h16     = wh + H_H16;
    _Float16* q16c    = wh + H_Q16C;
    _Float16* kT16    = wh + H_KT16;
    _Float16* vC16    = wh + H_VC16;
    float* gbuf = (float*)((char*)d_ws + HALF_BYTES) + F_G;

    // fused staging: pack1 + pack_flat x2 + pad + conv1x1 + border-zero
    staging_kernel<<<4544, 256, 0, stream>>>(
        wq_x, wq_h, wk_x, wk_h, wv_x, wv_h, wg_x, wg_h, wg_a, w_out,
        h0, x, w_in, b_in, apack1, apack2, apack3, xpad16, hpad16);

    // fused q/k/v/gates3x3 GEMM: M=1792, K=4608, N=576 x 16 batches (n-pairs)
    gemm_kernel<0, 0, 2><<<dim3(9, 8, 7), 256, 0, stream>>>(
        apack1, xpad16, hpad16, q16c, kT16, vC16, gbuf, bv, nullptr, nullptr, kKT1, 0);

    // MFMA flash attention -> a16 [n][px][256]
    attn_kernel<<<dim3(9, 128), 128, 0, stream>>>(q16c, kT16, vC16, a16);

    // gates = wg_a . a + bg + gbuf, fused LSTM -> h16 [n][px][256]  (single-n, 576 blocks)
    gemm_kernel<1, 3, 1><<<dim3(9, 16, 4), 256, 0, stream>>>(
        apack2, a16, nullptr, nullptr, nullptr, nullptr, gbuf, bg, c0, h16, kKT2, 256);

    // out = w_out . h + b_out : M=256 -> 1 m-tile  (single-n, 144 blocks)
    gemm_kernel<1, 2, 1><<<dim3(9, 16, 1), 256, 0, stream>>>(
        apack3, h16, nullptr, nullptr, nullptr, nullptr, (float*)d_out, b_out, nullptr, nullptr, kKT3, 256);
}